// Round 4
// baseline (818.637 us; speedup 1.0000x reference)
//
#include <hip/hip_runtime.h>
#include <cstdint>

#define EPSF 1e-15f
#define MAXN (1.0f - 1e-5f)

__device__ __forceinline__ float wsum64(float v) {
    v += __shfl_xor(v, 1);
    v += __shfl_xor(v, 2);
    v += __shfl_xor(v, 4);
    v += __shfl_xor(v, 8);
    v += __shfl_xor(v, 16);
    v += __shfl_xor(v, 32);
    return v;
}

__device__ __forceinline__ float dot4(float4 a, float4 b) {
    return a.x * b.x + a.y * b.y + a.z * b.z + a.w * b.w;
}

// degree histogram over kg_src
__global__ void kg_hist_k(const int* __restrict__ src, int* __restrict__ deg, int nE) {
    int e = blockIdx.x * blockDim.x + threadIdx.x;
    if (e < nE) atomicAdd(&deg[src[e]], 1);
}

// contiguous segment allocation via atomic offset (order-free CSR)
__global__ void kg_alloc_k(const int* __restrict__ deg, int* __restrict__ base,
                           int* __restrict__ cursor, int* __restrict__ gtotal, int n) {
    int i = blockIdx.x * blockDim.x + threadIdx.x;
    if (i < n) {
        int b = atomicAdd(gtotal, deg[i]);
        base[i] = b;
        cursor[i] = b;
    }
}

// Coef + scatter: 16 lanes per edge (fully coalesced row reads).
// res = a*u + b*v + c*r ; payload = {b, c, a, pack(dst,typ)} at CSR slot of src.
__global__ __launch_bounds__(256) void kg_coef_k(const float* __restrict__ ent,
                          const float* __restrict__ rel,
                          const int* __restrict__ src,
                          const int* __restrict__ dst,
                          const int* __restrict__ typ,
                          int* __restrict__ cursor,
                          float4* __restrict__ payload,
                          int nE) {
    int e = (blockIdx.x << 4) + (threadIdx.x >> 4);
    if (e >= nE) return;
    int j = threadIdx.x & 15;
    int s = src[e], d = dst[e], ty = typ[e] + 2;

    float4 av = ((const float4*)(ent + (size_t)s * 64))[j];
    float4 bv = ((const float4*)(ent + (size_t)d * 64))[j];
    float4 cv = ((const float4*)(rel + (size_t)ty * 64))[j];

    float uu = dot4(av, av), vv = dot4(bv, bv), rr = dot4(cv, cv);
    float uv = dot4(av, bv), ur = dot4(av, cv), vr = dot4(bv, cv);
#pragma unroll
    for (int m = 1; m < 16; m <<= 1) {
        uu += __shfl_xor(uu, m);
        vv += __shfl_xor(vv, m);
        rr += __shfl_xor(rr, m);
        uv += __shfl_xor(uv, m);
        ur += __shfl_xor(ur, m);
        vr += __shfl_xor(vr, m);
    }

    // p = expmap0(u) = cp*u
    float n0 = sqrtf(fmaxf(uu, EPSF));
    float cp = tanhf(n0) / n0;
    float p2 = cp * cp * uu;
    float om_p2 = 1.f - p2;
    float lam = 2.f / fmaxf(om_p2, EPSF);

    // dh = expmap(v, p) = a1*u + b1*v
    float nv = sqrtf(fmaxf(vv, EPSF));
    float cd = tanhf(0.5f * lam * nv) / nv;
    float wd2 = cd * cd * vv;
    float pwd = cp * cd * uv;
    float Dd = fmaxf(1.f + 2.f * pwd + p2 * wd2, EPSF);
    float a1 = (1.f + 2.f * pwd + wd2) * cp / Dd;
    float b1 = om_p2 * cd / Dd;

    // rh = expmap(r, p) = a2*u + c2*r
    float nr = sqrtf(fmaxf(rr, EPSF));
    float cr = tanhf(0.5f * lam * nr) / nr;
    float wr2 = cr * cr * rr;
    float pwr = cp * cr * ur;
    float Dr = fmaxf(1.f + 2.f * pwr + p2 * wr2, EPSF);
    float a2 = (1.f + 2.f * pwr + wr2) * cp / Dr;
    float c2 = om_p2 * cr / Dr;

    // mobius_add(dh, rh): z = zu*u + zv*v + zr*r
    float x2 = a1 * a1 * uu + 2.f * a1 * b1 * uv + b1 * b1 * vv;
    float y2 = a2 * a2 * uu + 2.f * a2 * c2 * ur + c2 * c2 * rr;
    float xy = a1 * a2 * uu + a1 * c2 * ur + b1 * a2 * uv + b1 * c2 * vr;
    float den = fmaxf(1.f + 2.f * xy + x2 * y2, EPSF);
    float E = (1.f + 2.f * xy + y2) / den;
    float F = (1.f - x2) / den;
    float zu = E * a1 + F * a2;
    float zv = E * b1;
    float zr = F * c2;

    // project(z)
    float z2 = zu * zu * uu + zv * zv * vv + zr * zr * rr
             + 2.f * (zu * zv * uv + zu * zr * ur + zv * zr * vr);
    float nz = sqrtf(fmaxf(z2, EPSF));
    if (nz > MAXN) {
        float sc = MAXN / nz;
        zu *= sc; zv *= sc; zr *= sc;
        z2 *= sc * sc;
    }

    // sub = mobius_add(-p, z) = su*u + sv*v + sr*r
    float mxy = -cp * (zu * uu + zv * uv + zr * ur);
    float denl = fmaxf(1.f + 2.f * mxy + p2 * z2, EPSF);
    float G = (1.f + 2.f * mxy + z2) / denl;
    float H = om_p2 / denl;
    float su = -G * cp + H * zu;
    float sv = H * zv;
    float sr = H * zr;

    float ns2 = su * su * uu + sv * sv * vv + sr * sr * rr
              + 2.f * (su * sv * uv + su * sr * ur + sv * sr * vr);
    float ns = sqrtf(fmaxf(ns2, EPSF));
    float k = fmaxf(om_p2, EPSF) * atanhf(fminf(ns, MAXN)) / ns;

    if (j == 0) {
        int pos = atomicAdd(&cursor[s], 1);
        payload[pos] = make_float4(k * sv, k * sr, k * su,
                                   __int_as_float(d | (ty << 18)));
    }
}

// Wave-per-entity CSR gather: out = (sum_e b*v + c*r + (sum_e a)*u) / max(deg,1)
// Writes directly to d_out chunks (no atomics, no out_div pass).
__global__ void kg_gather_k(const float* __restrict__ ent,
                            const float* __restrict__ rel,
                            const int* __restrict__ deg,
                            const int* __restrict__ base,
                            const float4* __restrict__ payload,
                            float* __restrict__ out_final,
                            float* __restrict__ out_items,
                            int n_items, int n) {
    int i = blockIdx.x * (blockDim.x >> 6) + (threadIdx.x >> 6);
    if (i >= n) return;
    int l = threadIdx.x & 63;
    int b = base[i], dg = deg[i];
    float acc = 0.f, as = 0.f;
    for (int q = 0; q < dg; ++q) {
        float4 p = payload[b + q];
        int w = __float_as_int(p.w);
        int d = w & 0x3FFFF, t = w >> 18;
        acc += p.x * ent[(size_t)d * 64 + l] + p.y * rel[(size_t)t * 64 + l];
        as += p.z;
    }
    float v = (acc + as * ent[(size_t)i * 64 + l]) / fmaxf((float)dg, 1.f);
    if (i < n_items) out_items[(size_t)i * 64 + l] = v;
    else             out_final[(size_t)i * 64 + l] = v;
}

// norm_all[j] = sum_d cat_nodes[j,d]^2 ; wave per node
__global__ void norm_k(const float* __restrict__ items, const float* __restrict__ user,
                       float* __restrict__ normv, int n_items, int N) {
    int j = blockIdx.x * (blockDim.x >> 6) + (threadIdx.x >> 6);
    if (j >= N) return;
    int l = threadIdx.x & 63;
    float c = (j < n_items) ? items[(size_t)j * 64 + l]
                            : user[(size_t)(j - n_items) * 64 + l];
    float s = wsum64(c * c);
    if (l == 0) normv[j] = s;
}

// item->user pass, 4-edge ILP per wave
__global__ void iu_k(const float* __restrict__ items, const float* __restrict__ user,
                     const int* __restrict__ srcA, const int* __restrict__ dstA,
                     float* __restrict__ usum, float* __restrict__ ucnt,
                     int n_items, int N, int nE) {
    int w = blockIdx.x * (blockDim.x >> 6) + (threadIdx.x >> 6);
    int l = threadIdx.x & 63;
    int base = w * 4;
    float v[4]; int dd[4]; bool ok[4];
#pragma unroll
    for (int j = 0; j < 4; ++j) {
        int e = base + j;
        ok[j] = false; dd[j] = 0; v[j] = 0.f;
        if (e < nE) {
            int d = dstA[e];
            if (d >= n_items && d < N) {
                int s = srcA[e];
                ok[j] = true; dd[j] = d - n_items;
                v[j] = (s < n_items) ? items[(size_t)s * 64 + l]
                                     : user[(size_t)(s - n_items) * 64 + l];
            }
        }
    }
#pragma unroll
    for (int j = 0; j < 4; ++j) {
        if (ok[j]) {
            atomicAdd(&usum[(size_t)dd[j] * 64 + l], v[j]);
            if (l == 0) atomicAdd(&ucnt[dd[j]], 1.f);
        }
    }
}

// user->item pass, 4-edge ILP: msg = cat[s]/(norm[s]+1e-6) * norm[d]
__global__ void ui_k(const float* __restrict__ items, const float* __restrict__ user,
                     const float* __restrict__ normv,
                     const int* __restrict__ srcA, const int* __restrict__ dstA,
                     float* __restrict__ isum, float* __restrict__ icnt,
                     int n_items, int nE) {
    int w = blockIdx.x * (blockDim.x >> 6) + (threadIdx.x >> 6);
    int l = threadIdx.x & 63;
    int base = w * 4;
    float v[4]; int dd[4]; bool ok[4];
#pragma unroll
    for (int j = 0; j < 4; ++j) {
        int e = base + j;
        ok[j] = false; dd[j] = 0; v[j] = 0.f;
        if (e < nE) {
            int d = dstA[e];
            if (d < n_items) {
                int s = srcA[e];
                float f = normv[d] / (normv[s] + 1e-6f);
                ok[j] = true; dd[j] = d;
                float raw = (s < n_items) ? items[(size_t)s * 64 + l]
                                          : user[(size_t)(s - n_items) * 64 + l];
                v[j] = f * raw;
            }
        }
    }
#pragma unroll
    for (int j = 0; j < 4; ++j) {
        if (ok[j]) {
            atomicAdd(&isum[(size_t)dd[j] * 64 + l], v[j]);
            if (l == 0) atomicAdd(&icnt[dd[j]], 1.f);
        }
    }
}

__global__ void u_div_k(const float* __restrict__ usum, const float* __restrict__ ucnt,
                        float* __restrict__ uout, long total) {
    long idx = (long)blockIdx.x * blockDim.x + threadIdx.x;
    if (idx >= total) return;
    uout[idx] = usum[idx] / fmaxf(ucnt[idx >> 6], 1.f);
}

// gate + fusion: gi = sigmoid(oi@W1.T + icf@W2.T); out = gi*oi + (1-gi)*icf
__global__ __launch_bounds__(256) void fusion_k(const float* __restrict__ items,
                         const float* __restrict__ isum, const float* __restrict__ icnt,
                         const float* __restrict__ W1, const float* __restrict__ W2,
                         float* __restrict__ outf, int n_items) {
    __shared__ float W1s[64][65];
    __shared__ float W2s[64][65];
    for (int idx = threadIdx.x; idx < 4096; idx += blockDim.x) {
        W1s[idx >> 6][idx & 63] = W1[idx];
        W2s[idx >> 6][idx & 63] = W2[idx];
    }
    __syncthreads();
    int i = blockIdx.x * (blockDim.x >> 6) + (threadIdx.x >> 6);
    if (i >= n_items) return;
    int j = threadIdx.x & 63;
    float oi = items[(size_t)i * 64 + j];
    float cf = isum[(size_t)i * 64 + j] / fmaxf(icnt[i], 1.f);
    float acc = 0.f;
#pragma unroll 8
    for (int k = 0; k < 64; ++k) {
        acc += __shfl(oi, k) * W1s[j][k] + __shfl(cf, k) * W2s[j][k];
    }
    float g = 1.f / (1.f + expf(-acc));
    outf[(size_t)i * 64 + j] = g * oi + (1.f - g) * cf;
}

extern "C" void kernel_launch(void* const* d_in, const int* in_sizes, int n_in,
                              void* d_out, int out_size, void* d_ws, size_t ws_size,
                              hipStream_t stream) {
    const float* ent    = (const float*)d_in[0];
    const float* usr    = (const float*)d_in[1];
    const float* rel    = (const float*)d_in[2];
    const float* W1     = (const float*)d_in[3];
    const float* W2     = (const float*)d_in[4];
    const int*   kg_src = (const int*)d_in[5];
    const int*   kg_dst = (const int*)d_in[6];
    const int*   kg_typ = (const int*)d_in[7];
    const int*   iu_src = (const int*)d_in[8];
    const int*   iu_dst = (const int*)d_in[9];
    const int*   ui_src = (const int*)d_in[10];
    const int*   ui_dst = (const int*)d_in[11];

    const int n_ent   = in_sizes[0] / 64;
    const int n_usr   = in_sizes[1] / 64;
    const int E_kg    = in_sizes[5];
    const int E_iu    = in_sizes[8];
    const int E_ui    = in_sizes[10];
    const int n_items = (out_size - in_sizes[0] - in_sizes[1]) / 64;
    const int N       = n_items + n_usr;

    float* out_final = (float*)d_out;                        // (n_ent,64)
    float* out_u     = out_final + (size_t)n_ent * 64;       // (n_usr,64)
    float* out_items = out_u + (size_t)n_usr * 64;           // (n_items,64)

    float* ws = (float*)d_ws;
    size_t o = 0;
    int*   deg    = (int*)(ws + o);  o += n_ent;
    int*   gtotal = (int*)(ws + o);  o += 1;       // contiguous with deg for memset
    int*   basep  = (int*)(ws + o);  o += n_ent;
    int*   cursor = (int*)(ws + o);  o += n_ent;
    o = (o + 3) & ~(size_t)3;                      // 16B align for float4
    float4* payload = (float4*)(ws + o); o += (size_t)E_kg * 4;
    float* usum  = ws + o;          size_t z2_start = o;
                                    o += (size_t)n_usr * 64;
    float* ucnt  = ws + o;          o += n_usr;
    float* isum  = ws + o;          o += (size_t)n_items * 64;
    float* icnt  = ws + o;          o += n_items;
    float* normv = ws + o;          o += N;
    size_t z2_len = ((size_t)n_usr * 65 + (size_t)n_items * 65) * sizeof(float);

    // zero degree histogram + gtotal
    hipMemsetAsync(deg, 0, ((size_t)n_ent + 1) * sizeof(int), stream);

    kg_hist_k<<<(E_kg + 255) / 256, 256, 0, stream>>>(kg_src, deg, E_kg);
    kg_alloc_k<<<(n_ent + 255) / 256, 256, 0, stream>>>(deg, basep, cursor, gtotal, n_ent);
    kg_coef_k<<<(E_kg + 15) / 16, 256, 0, stream>>>(ent, rel, kg_src, kg_dst, kg_typ,
                                                    cursor, payload, E_kg);
    kg_gather_k<<<(n_ent + 3) / 4, 256, 0, stream>>>(ent, rel, deg, basep, payload,
                                                     out_final, out_items, n_items, n_ent);

    norm_k<<<(N + 3) / 4, 256, 0, stream>>>(out_items, usr, normv, n_items, N);

    // zero CF accumulators (usum,ucnt,isum,icnt contiguous)
    hipMemsetAsync(ws + z2_start, 0, z2_len, stream);

    iu_k<<<(E_iu + 15) / 16, 256, 0, stream>>>(out_items, usr, iu_src, iu_dst,
                                               usum, ucnt, n_items, N, E_iu);
    ui_k<<<(E_ui + 15) / 16, 256, 0, stream>>>(out_items, usr, normv, ui_src, ui_dst,
                                               isum, icnt, n_items, E_ui);
    u_div_k<<<(int)(((size_t)n_usr * 64 + 255) / 256), 256, 0, stream>>>(
        usum, ucnt, out_u, (long)n_usr * 64);
    fusion_k<<<(n_items + 3) / 4, 256, 0, stream>>>(out_items, isum, icnt,
                                                    W1, W2, out_final, n_items);
}

// Round 5
// 699.706 us; speedup vs baseline: 1.1700x; 1.1700x over previous
//
#include <hip/hip_runtime.h>
#include <cstdint>

#define EPSF 1e-15f
#define MAXN (1.0f - 1e-5f)

__device__ __forceinline__ float wsum64(float v) {
    v += __shfl_xor(v, 1);
    v += __shfl_xor(v, 2);
    v += __shfl_xor(v, 4);
    v += __shfl_xor(v, 8);
    v += __shfl_xor(v, 16);
    v += __shfl_xor(v, 32);
    return v;
}

__device__ __forceinline__ float dot4(float4 a, float4 b) {
    return a.x * b.x + a.y * b.y + a.z * b.z + a.w * b.w;
}

// degree histogram over kg_src
__global__ void kg_hist_k(const int* __restrict__ src, int* __restrict__ deg, int nE) {
    int e = blockIdx.x * blockDim.x + threadIdx.x;
    if (e < nE) atomicAdd(&deg[src[e]], 1);
}

// contiguous segment allocation via atomic offset (order-free CSR)
__global__ void kg_alloc_k(const int* __restrict__ deg, int* __restrict__ base,
                           int* __restrict__ cursor, int* __restrict__ gtotal, int n) {
    int i = blockIdx.x * blockDim.x + threadIdx.x;
    if (i < n) {
        int b = atomicAdd(gtotal, deg[i]);
        base[i] = b;
        cursor[i] = b;
    }
}

// Gram-dots kernel: 4 lanes per edge; lane j0 reads float4 (4i+j0) so each
// load instruction consumes whole 64B lines. 2-step shfl reduce.
// dots -> dotsA[e]=(uu,vv,rr,uv), dotsB[e]=(ur,vr)
__global__ __launch_bounds__(256) void kg_dots_k(const float* __restrict__ ent,
                          const float* __restrict__ rel,
                          const int* __restrict__ src,
                          const int* __restrict__ dst,
                          const int* __restrict__ typ,
                          float4* __restrict__ dotsA,
                          float2* __restrict__ dotsB,
                          int nE) {
    int w = blockIdx.x * 4 + (threadIdx.x >> 6);
    int l = threadIdx.x & 63;
    int e = w * 16 + (l >> 2);
    if (e >= nE) return;
    int j0 = l & 3;
    const float4* pu = (const float4*)(ent + (size_t)src[e] * 64);
    const float4* pv = (const float4*)(ent + (size_t)dst[e] * 64);
    const float4* pr = (const float4*)(rel + (size_t)(typ[e] + 2) * 64);

    float uu = 0.f, vv = 0.f, rr = 0.f, uv = 0.f, ur = 0.f, vr = 0.f;
#pragma unroll
    for (int i = 0; i < 4; ++i) {
        float4 a = pu[4 * i + j0], b = pv[4 * i + j0], c = pr[4 * i + j0];
        uu += dot4(a, a); vv += dot4(b, b); rr += dot4(c, c);
        uv += dot4(a, b); ur += dot4(a, c); vr += dot4(b, c);
    }
#pragma unroll
    for (int m = 1; m < 4; m <<= 1) {
        uu += __shfl_xor(uu, m);
        vv += __shfl_xor(vv, m);
        rr += __shfl_xor(rr, m);
        uv += __shfl_xor(uv, m);
        ur += __shfl_xor(ur, m);
        vr += __shfl_xor(vr, m);
    }
    if (j0 == 0) dotsA[e] = make_float4(uu, vv, rr, uv);
    if (j0 == 1) dotsB[e] = make_float2(ur, vr);
}

// Chain kernel: thread-per-edge, scalar hyperbolic chain run ONCE per edge.
// payload = {b, c, a, pack(dst,typ)} at CSR slot of src.
__global__ __launch_bounds__(256) void kg_chain_k(const float4* __restrict__ dotsA,
                           const float2* __restrict__ dotsB,
                           const int* __restrict__ src,
                           const int* __restrict__ dst,
                           const int* __restrict__ typ,
                           int* __restrict__ cursor,
                           float4* __restrict__ payload,
                           int nE) {
    int e = blockIdx.x * blockDim.x + threadIdx.x;
    if (e >= nE) return;
    float4 dA = dotsA[e];
    float2 dB = dotsB[e];
    float uu = dA.x, vv = dA.y, rr = dA.z, uv = dA.w, ur = dB.x, vr = dB.y;
    int s = src[e], d = dst[e], ty = typ[e] + 2;

    // p = expmap0(u) = cp*u
    float n0 = sqrtf(fmaxf(uu, EPSF));
    float cp = tanhf(n0) / n0;
    float p2 = cp * cp * uu;
    float om_p2 = 1.f - p2;
    float lam = 2.f / fmaxf(om_p2, EPSF);

    // dh = expmap(v, p) = a1*u + b1*v
    float nv = sqrtf(fmaxf(vv, EPSF));
    float cd = tanhf(0.5f * lam * nv) / nv;
    float wd2 = cd * cd * vv;
    float pwd = cp * cd * uv;
    float Dd = fmaxf(1.f + 2.f * pwd + p2 * wd2, EPSF);
    float a1 = (1.f + 2.f * pwd + wd2) * cp / Dd;
    float b1 = om_p2 * cd / Dd;

    // rh = expmap(r, p) = a2*u + c2*r
    float nr = sqrtf(fmaxf(rr, EPSF));
    float cr = tanhf(0.5f * lam * nr) / nr;
    float wr2 = cr * cr * rr;
    float pwr = cp * cr * ur;
    float Dr = fmaxf(1.f + 2.f * pwr + p2 * wr2, EPSF);
    float a2 = (1.f + 2.f * pwr + wr2) * cp / Dr;
    float c2 = om_p2 * cr / Dr;

    // mobius_add(dh, rh): z = zu*u + zv*v + zr*r
    float x2 = a1 * a1 * uu + 2.f * a1 * b1 * uv + b1 * b1 * vv;
    float y2 = a2 * a2 * uu + 2.f * a2 * c2 * ur + c2 * c2 * rr;
    float xy = a1 * a2 * uu + a1 * c2 * ur + b1 * a2 * uv + b1 * c2 * vr;
    float den = fmaxf(1.f + 2.f * xy + x2 * y2, EPSF);
    float E = (1.f + 2.f * xy + y2) / den;
    float F = (1.f - x2) / den;
    float zu = E * a1 + F * a2;
    float zv = E * b1;
    float zr = F * c2;

    // project(z)
    float z2 = zu * zu * uu + zv * zv * vv + zr * zr * rr
             + 2.f * (zu * zv * uv + zu * zr * ur + zv * zr * vr);
    float nz = sqrtf(fmaxf(z2, EPSF));
    if (nz > MAXN) {
        float sc = MAXN / nz;
        zu *= sc; zv *= sc; zr *= sc;
        z2 *= sc * sc;
    }

    // sub = mobius_add(-p, z) = su*u + sv*v + sr*r
    float mxy = -cp * (zu * uu + zv * uv + zr * ur);
    float denl = fmaxf(1.f + 2.f * mxy + p2 * z2, EPSF);
    float G = (1.f + 2.f * mxy + z2) / denl;
    float H = om_p2 / denl;
    float su = -G * cp + H * zu;
    float sv = H * zv;
    float sr = H * zr;

    float ns2 = su * su * uu + sv * sv * vv + sr * sr * rr
              + 2.f * (su * sv * uv + su * sr * ur + sv * sr * vr);
    float ns = sqrtf(fmaxf(ns2, EPSF));
    float k = fmaxf(om_p2, EPSF) * atanhf(fminf(ns, MAXN)) / ns;

    int pos = atomicAdd(&cursor[s], 1);
    payload[pos] = make_float4(k * sv, k * sr, k * su,
                               __int_as_float(d | (ty << 18)));
}

// Wave-per-entity CSR gather: out = (sum_e b*v + c*r + (sum_e a)*u) / max(deg,1)
// Writes directly to d_out chunks (no atomics). 2x unrolled for load overlap.
__global__ void kg_gather_k(const float* __restrict__ ent,
                            const float* __restrict__ rel,
                            const int* __restrict__ deg,
                            const int* __restrict__ base,
                            const float4* __restrict__ payload,
                            float* __restrict__ out_final,
                            float* __restrict__ out_items,
                            int n_items, int n) {
    int i = blockIdx.x * (blockDim.x >> 6) + (threadIdx.x >> 6);
    if (i >= n) return;
    int l = threadIdx.x & 63;
    int b = base[i], dg = deg[i];
    float acc = 0.f, as = 0.f;
    int q = 0;
    for (; q + 2 <= dg; q += 2) {
        float4 p0 = payload[b + q];
        float4 p1 = payload[b + q + 1];
        int w0 = __float_as_int(p0.w), w1 = __float_as_int(p1.w);
        float v0 = ent[(size_t)(w0 & 0x3FFFF) * 64 + l];
        float r0 = rel[(size_t)(w0 >> 18) * 64 + l];
        float v1 = ent[(size_t)(w1 & 0x3FFFF) * 64 + l];
        float r1 = rel[(size_t)(w1 >> 18) * 64 + l];
        acc += p0.x * v0 + p0.y * r0;
        acc += p1.x * v1 + p1.y * r1;
        as += p0.z + p1.z;
    }
    if (q < dg) {
        float4 p = payload[b + q];
        int w = __float_as_int(p.w);
        acc += p.x * ent[(size_t)(w & 0x3FFFF) * 64 + l]
             + p.y * rel[(size_t)(w >> 18) * 64 + l];
        as += p.z;
    }
    float v = (acc + as * ent[(size_t)i * 64 + l]) / fmaxf((float)dg, 1.f);
    if (i < n_items) out_items[(size_t)i * 64 + l] = v;
    else             out_final[(size_t)i * 64 + l] = v;
}

// norm_all[j] = sum_d cat_nodes[j,d]^2 ; wave per node
__global__ void norm_k(const float* __restrict__ items, const float* __restrict__ user,
                       float* __restrict__ normv, int n_items, int N) {
    int j = blockIdx.x * (blockDim.x >> 6) + (threadIdx.x >> 6);
    if (j >= N) return;
    int l = threadIdx.x & 63;
    float c = (j < n_items) ? items[(size_t)j * 64 + l]
                            : user[(size_t)(j - n_items) * 64 + l];
    float s = wsum64(c * c);
    if (l == 0) normv[j] = s;
}

// item->user pass, 4-edge ILP per wave
__global__ void iu_k(const float* __restrict__ items, const float* __restrict__ user,
                     const int* __restrict__ srcA, const int* __restrict__ dstA,
                     float* __restrict__ usum, float* __restrict__ ucnt,
                     int n_items, int N, int nE) {
    int w = blockIdx.x * (blockDim.x >> 6) + (threadIdx.x >> 6);
    int l = threadIdx.x & 63;
    int base = w * 4;
    float v[4]; int dd[4]; bool ok[4];
#pragma unroll
    for (int j = 0; j < 4; ++j) {
        int e = base + j;
        ok[j] = false; dd[j] = 0; v[j] = 0.f;
        if (e < nE) {
            int d = dstA[e];
            if (d >= n_items && d < N) {
                int s = srcA[e];
                ok[j] = true; dd[j] = d - n_items;
                v[j] = (s < n_items) ? items[(size_t)s * 64 + l]
                                     : user[(size_t)(s - n_items) * 64 + l];
            }
        }
    }
#pragma unroll
    for (int j = 0; j < 4; ++j) {
        if (ok[j]) {
            atomicAdd(&usum[(size_t)dd[j] * 64 + l], v[j]);
            if (l == 0) atomicAdd(&ucnt[dd[j]], 1.f);
        }
    }
}

// user->item pass, 4-edge ILP: msg = cat[s]/(norm[s]+1e-6) * norm[d]
__global__ void ui_k(const float* __restrict__ items, const float* __restrict__ user,
                     const float* __restrict__ normv,
                     const int* __restrict__ srcA, const int* __restrict__ dstA,
                     float* __restrict__ isum, float* __restrict__ icnt,
                     int n_items, int nE) {
    int w = blockIdx.x * (blockDim.x >> 6) + (threadIdx.x >> 6);
    int l = threadIdx.x & 63;
    int base = w * 4;
    float v[4]; int dd[4]; bool ok[4];
#pragma unroll
    for (int j = 0; j < 4; ++j) {
        int e = base + j;
        ok[j] = false; dd[j] = 0; v[j] = 0.f;
        if (e < nE) {
            int d = dstA[e];
            if (d < n_items) {
                int s = srcA[e];
                float f = normv[d] / (normv[s] + 1e-6f);
                ok[j] = true; dd[j] = d;
                float raw = (s < n_items) ? items[(size_t)s * 64 + l]
                                          : user[(size_t)(s - n_items) * 64 + l];
                v[j] = f * raw;
            }
        }
    }
#pragma unroll
    for (int j = 0; j < 4; ++j) {
        if (ok[j]) {
            atomicAdd(&isum[(size_t)dd[j] * 64 + l], v[j]);
            if (l == 0) atomicAdd(&icnt[dd[j]], 1.f);
        }
    }
}

__global__ void u_div_k(const float* __restrict__ usum, const float* __restrict__ ucnt,
                        float* __restrict__ uout, long total) {
    long idx = (long)blockIdx.x * blockDim.x + threadIdx.x;
    if (idx >= total) return;
    uout[idx] = usum[idx] / fmaxf(ucnt[idx >> 6], 1.f);
}

// gate + fusion: gi = sigmoid(oi@W1.T + icf@W2.T); out = gi*oi + (1-gi)*icf
__global__ __launch_bounds__(256) void fusion_k(const float* __restrict__ items,
                         const float* __restrict__ isum, const float* __restrict__ icnt,
                         const float* __restrict__ W1, const float* __restrict__ W2,
                         float* __restrict__ outf, int n_items) {
    __shared__ float W1s[64][65];
    __shared__ float W2s[64][65];
    for (int idx = threadIdx.x; idx < 4096; idx += blockDim.x) {
        W1s[idx >> 6][idx & 63] = W1[idx];
        W2s[idx >> 6][idx & 63] = W2[idx];
    }
    __syncthreads();
    int i = blockIdx.x * (blockDim.x >> 6) + (threadIdx.x >> 6);
    if (i >= n_items) return;
    int j = threadIdx.x & 63;
    float oi = items[(size_t)i * 64 + j];
    float cf = isum[(size_t)i * 64 + j] / fmaxf(icnt[i], 1.f);
    float acc = 0.f;
#pragma unroll 8
    for (int k = 0; k < 64; ++k) {
        acc += __shfl(oi, k) * W1s[j][k] + __shfl(cf, k) * W2s[j][k];
    }
    float g = 1.f / (1.f + expf(-acc));
    outf[(size_t)i * 64 + j] = g * oi + (1.f - g) * cf;
}

extern "C" void kernel_launch(void* const* d_in, const int* in_sizes, int n_in,
                              void* d_out, int out_size, void* d_ws, size_t ws_size,
                              hipStream_t stream) {
    const float* ent    = (const float*)d_in[0];
    const float* usr    = (const float*)d_in[1];
    const float* rel    = (const float*)d_in[2];
    const float* W1     = (const float*)d_in[3];
    const float* W2     = (const float*)d_in[4];
    const int*   kg_src = (const int*)d_in[5];
    const int*   kg_dst = (const int*)d_in[6];
    const int*   kg_typ = (const int*)d_in[7];
    const int*   iu_src = (const int*)d_in[8];
    const int*   iu_dst = (const int*)d_in[9];
    const int*   ui_src = (const int*)d_in[10];
    const int*   ui_dst = (const int*)d_in[11];

    const int n_ent   = in_sizes[0] / 64;
    const int n_usr   = in_sizes[1] / 64;
    const int E_kg    = in_sizes[5];
    const int E_iu    = in_sizes[8];
    const int E_ui    = in_sizes[10];
    const int n_items = (out_size - in_sizes[0] - in_sizes[1]) / 64;
    const int N       = n_items + n_usr;

    float* out_final = (float*)d_out;                        // (n_ent,64)
    float* out_u     = out_final + (size_t)n_ent * 64;       // (n_usr,64)
    float* out_items = out_u + (size_t)n_usr * 64;           // (n_items,64)

    // dots scratch lives in d_out's entity chunk: 24B/edge (19.2MB < 25.6MB).
    // Written by kg_dots_k, consumed by kg_chain_k, then overwritten by
    // kg_gather_k (rows >= n_items) and fusion_k (rows < n_items).
    float4* dotsA = (float4*)d_out;                          // E_kg * 16B
    float2* dotsB = (float2*)((float*)d_out + (size_t)E_kg * 4); // E_kg * 8B

    float* ws = (float*)d_ws;
    size_t o = 0;
    int*   deg    = (int*)(ws + o);  o += n_ent;
    int*   gtotal = (int*)(ws + o);  o += 1;       // contiguous with deg for memset
    int*   basep  = (int*)(ws + o);  o += n_ent;
    int*   cursor = (int*)(ws + o);  o += n_ent;
    o = (o + 3) & ~(size_t)3;                      // 16B align for float4
    float4* payload = (float4*)(ws + o); o += (size_t)E_kg * 4;
    float* usum  = ws + o;          size_t z2_start = o;
                                    o += (size_t)n_usr * 64;
    float* ucnt  = ws + o;          o += n_usr;
    float* isum  = ws + o;          o += (size_t)n_items * 64;
    float* icnt  = ws + o;          o += n_items;
    float* normv = ws + o;          o += N;
    size_t z2_len = ((size_t)n_usr * 65 + (size_t)n_items * 65) * sizeof(float);

    // zero degree histogram + gtotal
    hipMemsetAsync(deg, 0, ((size_t)n_ent + 1) * sizeof(int), stream);

    kg_hist_k<<<(E_kg + 255) / 256, 256, 0, stream>>>(kg_src, deg, E_kg);
    kg_alloc_k<<<(n_ent + 255) / 256, 256, 0, stream>>>(deg, basep, cursor, gtotal, n_ent);
    kg_dots_k<<<(E_kg + 63) / 64, 256, 0, stream>>>(ent, rel, kg_src, kg_dst, kg_typ,
                                                    dotsA, dotsB, E_kg);
    kg_chain_k<<<(E_kg + 255) / 256, 256, 0, stream>>>(dotsA, dotsB, kg_src, kg_dst,
                                                       kg_typ, cursor, payload, E_kg);
    kg_gather_k<<<(n_ent + 3) / 4, 256, 0, stream>>>(ent, rel, deg, basep, payload,
                                                     out_final, out_items, n_items, n_ent);

    norm_k<<<(N + 3) / 4, 256, 0, stream>>>(out_items, usr, normv, n_items, N);

    // zero CF accumulators (usum,ucnt,isum,icnt contiguous)
    hipMemsetAsync(ws + z2_start, 0, z2_len, stream);

    iu_k<<<(E_iu + 15) / 16, 256, 0, stream>>>(out_items, usr, iu_src, iu_dst,
                                               usum, ucnt, n_items, N, E_iu);
    ui_k<<<(E_ui + 15) / 16, 256, 0, stream>>>(out_items, usr, normv, ui_src, ui_dst,
                                               isum, icnt, n_items, E_ui);
    u_div_k<<<(int)(((size_t)n_usr * 64 + 255) / 256), 256, 0, stream>>>(
        usum, ucnt, out_u, (long)n_usr * 64);
    fusion_k<<<(n_items + 3) / 4, 256, 0, stream>>>(out_items, isum, icnt,
                                                    W1, W2, out_final, n_items);
}

// Round 6
// 518.030 us; speedup vs baseline: 1.5803x; 1.3507x over previous
//
#include <hip/hip_runtime.h>
#include <cstdint>

#define EPSF 1e-15f
#define MAXN (1.0f - 1e-5f)

__device__ __forceinline__ float wsum64(float v) {
    v += __shfl_xor(v, 1);
    v += __shfl_xor(v, 2);
    v += __shfl_xor(v, 4);
    v += __shfl_xor(v, 8);
    v += __shfl_xor(v, 16);
    v += __shfl_xor(v, 32);
    return v;
}

__device__ __forceinline__ float dot4(float4 a, float4 b) {
    return a.x * b.x + a.y * b.y + a.z * b.z + a.w * b.w;
}

// generic degree histogram with range filter: idx in [lo,hi) -> deg[idx-lo]++
__global__ void hist_k(const int* __restrict__ idx, int* __restrict__ deg,
                       int lo, int hi, int nE) {
    int e = blockIdx.x * blockDim.x + threadIdx.x;
    if (e >= nE) return;
    int d = idx[e];
    if (d >= lo && d < hi) atomicAdd(&deg[d - lo], 1);
}

// contiguous segment allocation via atomic offset (order-free CSR)
__global__ void alloc_k(const int* __restrict__ deg, int* __restrict__ base,
                        int* __restrict__ cursor, int* __restrict__ gtotal, int n) {
    int i = blockIdx.x * blockDim.x + threadIdx.x;
    if (i < n) {
        int b = atomicAdd(gtotal, deg[i]);
        base[i] = b;
        cursor[i] = b;
    }
}

// ---------------- KG path ----------------

// Gram-dots kernel: 4 lanes per edge; lane j0 reads float4 (4i+j0) so each
// load instruction consumes whole 64B lines. 2-step shfl reduce.
__global__ __launch_bounds__(256) void kg_dots_k(const float* __restrict__ ent,
                          const float* __restrict__ rel,
                          const int* __restrict__ src,
                          const int* __restrict__ dst,
                          const int* __restrict__ typ,
                          float4* __restrict__ dotsA,
                          float2* __restrict__ dotsB,
                          int nE) {
    int w = blockIdx.x * 4 + (threadIdx.x >> 6);
    int l = threadIdx.x & 63;
    int e = w * 16 + (l >> 2);
    if (e >= nE) return;
    int j0 = l & 3;
    const float4* pu = (const float4*)(ent + (size_t)src[e] * 64);
    const float4* pv = (const float4*)(ent + (size_t)dst[e] * 64);
    const float4* pr = (const float4*)(rel + (size_t)(typ[e] + 2) * 64);

    float uu = 0.f, vv = 0.f, rr = 0.f, uv = 0.f, ur = 0.f, vr = 0.f;
#pragma unroll
    for (int i = 0; i < 4; ++i) {
        float4 a = pu[4 * i + j0], b = pv[4 * i + j0], c = pr[4 * i + j0];
        uu += dot4(a, a); vv += dot4(b, b); rr += dot4(c, c);
        uv += dot4(a, b); ur += dot4(a, c); vr += dot4(b, c);
    }
#pragma unroll
    for (int m = 1; m < 4; m <<= 1) {
        uu += __shfl_xor(uu, m);
        vv += __shfl_xor(vv, m);
        rr += __shfl_xor(rr, m);
        uv += __shfl_xor(uv, m);
        ur += __shfl_xor(ur, m);
        vr += __shfl_xor(vr, m);
    }
    if (j0 == 0) dotsA[e] = make_float4(uu, vv, rr, uv);
    if (j0 == 1) dotsB[e] = make_float2(ur, vr);
}

// Chain kernel: thread-per-edge, scalar hyperbolic chain run ONCE per edge.
// payload = {b, c, a, pack(dst,typ)} at CSR slot of src.
__global__ __launch_bounds__(256) void kg_chain_k(const float4* __restrict__ dotsA,
                           const float2* __restrict__ dotsB,
                           const int* __restrict__ src,
                           const int* __restrict__ dst,
                           const int* __restrict__ typ,
                           int* __restrict__ cursor,
                           float4* __restrict__ payload,
                           int nE) {
    int e = blockIdx.x * blockDim.x + threadIdx.x;
    if (e >= nE) return;
    float4 dA = dotsA[e];
    float2 dB = dotsB[e];
    float uu = dA.x, vv = dA.y, rr = dA.z, uv = dA.w, ur = dB.x, vr = dB.y;
    int s = src[e], d = dst[e], ty = typ[e] + 2;

    float n0 = sqrtf(fmaxf(uu, EPSF));
    float cp = tanhf(n0) / n0;
    float p2 = cp * cp * uu;
    float om_p2 = 1.f - p2;
    float lam = 2.f / fmaxf(om_p2, EPSF);

    float nv = sqrtf(fmaxf(vv, EPSF));
    float cd = tanhf(0.5f * lam * nv) / nv;
    float wd2 = cd * cd * vv;
    float pwd = cp * cd * uv;
    float Dd = fmaxf(1.f + 2.f * pwd + p2 * wd2, EPSF);
    float a1 = (1.f + 2.f * pwd + wd2) * cp / Dd;
    float b1 = om_p2 * cd / Dd;

    float nr = sqrtf(fmaxf(rr, EPSF));
    float cr = tanhf(0.5f * lam * nr) / nr;
    float wr2 = cr * cr * rr;
    float pwr = cp * cr * ur;
    float Dr = fmaxf(1.f + 2.f * pwr + p2 * wr2, EPSF);
    float a2 = (1.f + 2.f * pwr + wr2) * cp / Dr;
    float c2 = om_p2 * cr / Dr;

    float x2 = a1 * a1 * uu + 2.f * a1 * b1 * uv + b1 * b1 * vv;
    float y2 = a2 * a2 * uu + 2.f * a2 * c2 * ur + c2 * c2 * rr;
    float xy = a1 * a2 * uu + a1 * c2 * ur + b1 * a2 * uv + b1 * c2 * vr;
    float den = fmaxf(1.f + 2.f * xy + x2 * y2, EPSF);
    float E = (1.f + 2.f * xy + y2) / den;
    float F = (1.f - x2) / den;
    float zu = E * a1 + F * a2;
    float zv = E * b1;
    float zr = F * c2;

    float z2 = zu * zu * uu + zv * zv * vv + zr * zr * rr
             + 2.f * (zu * zv * uv + zu * zr * ur + zv * zr * vr);
    float nz = sqrtf(fmaxf(z2, EPSF));
    if (nz > MAXN) {
        float sc = MAXN / nz;
        zu *= sc; zv *= sc; zr *= sc;
        z2 *= sc * sc;
    }

    float mxy = -cp * (zu * uu + zv * uv + zr * ur);
    float denl = fmaxf(1.f + 2.f * mxy + p2 * z2, EPSF);
    float G = (1.f + 2.f * mxy + z2) / denl;
    float H = om_p2 / denl;
    float su = -G * cp + H * zu;
    float sv = H * zv;
    float sr = H * zr;

    float ns2 = su * su * uu + sv * sv * vv + sr * sr * rr
              + 2.f * (su * sv * uv + su * sr * ur + sv * sr * vr);
    float ns = sqrtf(fmaxf(ns2, EPSF));
    float k = fmaxf(om_p2, EPSF) * atanhf(fminf(ns, MAXN)) / ns;

    int pos = atomicAdd(&cursor[s], 1);
    payload[pos] = make_float4(k * sv, k * sr, k * su,
                               __int_as_float(d | (ty << 18)));
}

// Wave-per-entity CSR gather: out = (sum_e b*v + c*r + (sum_e a)*u) / max(deg,1)
__global__ void kg_gather_k(const float* __restrict__ ent,
                            const float* __restrict__ rel,
                            const int* __restrict__ deg,
                            const int* __restrict__ base,
                            const float4* __restrict__ payload,
                            float* __restrict__ out_final,
                            float* __restrict__ out_items,
                            int n_items, int n) {
    int i = blockIdx.x * (blockDim.x >> 6) + (threadIdx.x >> 6);
    if (i >= n) return;
    int l = threadIdx.x & 63;
    int b = base[i], dg = deg[i];
    float acc = 0.f, as = 0.f;
    int q = 0;
    for (; q + 2 <= dg; q += 2) {
        float4 p0 = payload[b + q];
        float4 p1 = payload[b + q + 1];
        int w0 = __float_as_int(p0.w), w1 = __float_as_int(p1.w);
        float v0 = ent[(size_t)(w0 & 0x3FFFF) * 64 + l];
        float r0 = rel[(size_t)(w0 >> 18) * 64 + l];
        float v1 = ent[(size_t)(w1 & 0x3FFFF) * 64 + l];
        float r1 = rel[(size_t)(w1 >> 18) * 64 + l];
        acc += p0.x * v0 + p0.y * r0;
        acc += p1.x * v1 + p1.y * r1;
        as += p0.z + p1.z;
    }
    if (q < dg) {
        float4 p = payload[b + q];
        int w = __float_as_int(p.w);
        acc += p.x * ent[(size_t)(w & 0x3FFFF) * 64 + l]
             + p.y * rel[(size_t)(w >> 18) * 64 + l];
        as += p.z;
    }
    float v = (acc + as * ent[(size_t)i * 64 + l]) / fmaxf((float)dg, 1.f);
    if (i < n_items) out_items[(size_t)i * 64 + l] = v;
    else             out_final[(size_t)i * 64 + l] = v;
}

// ---------------- CF path ----------------

// norm_all[j] = sum_d cat_nodes[j,d]^2 ; wave per node
__global__ void norm_k(const float* __restrict__ items, const float* __restrict__ user,
                       float* __restrict__ normv, int n_items, int N) {
    int j = blockIdx.x * (blockDim.x >> 6) + (threadIdx.x >> 6);
    if (j >= N) return;
    int l = threadIdx.x & 63;
    float c = (j < n_items) ? items[(size_t)j * 64 + l]
                            : user[(size_t)(j - n_items) * 64 + l];
    float s = wsum64(c * c);
    if (l == 0) normv[j] = s;
}

// iu scatter: payload = src index at CSR slot of (dst - n_items)
__global__ void iu_scat_k(const int* __restrict__ srcA, const int* __restrict__ dstA,
                          int* __restrict__ cursor, int* __restrict__ payload,
                          int n_items, int N, int nE) {
    int e = blockIdx.x * blockDim.x + threadIdx.x;
    if (e >= nE) return;
    int d = dstA[e];
    if (d < n_items || d >= N) return;
    int pos = atomicAdd(&cursor[d - n_items], 1);
    payload[pos] = srcA[e];
}

// ui scatter: payload = {src, 1/(norm[src]+1e-6)} at CSR slot of dst
__global__ void ui_scat_k(const int* __restrict__ srcA, const int* __restrict__ dstA,
                          const float* __restrict__ normv,
                          int* __restrict__ cursor, float2* __restrict__ payload,
                          int n_items, int nE) {
    int e = blockIdx.x * blockDim.x + threadIdx.x;
    if (e >= nE) return;
    int d = dstA[e];
    if (d >= n_items) return;
    int s = srcA[e];
    int pos = atomicAdd(&cursor[d], 1);
    payload[pos] = make_float2(__int_as_float(s), 1.f / (normv[s] + 1e-6f));
}

// wave-per-user gather: out_u = (sum_e cat[src_e]) / max(deg,1), direct write
__global__ void iu_gather_k(const float* __restrict__ items, const float* __restrict__ user,
                            const int* __restrict__ deg, const int* __restrict__ base,
                            const int* __restrict__ payload,
                            float* __restrict__ out_u, int n_items, int n) {
    int i = blockIdx.x * (blockDim.x >> 6) + (threadIdx.x >> 6);
    if (i >= n) return;
    int l = threadIdx.x & 63;
    int b = base[i], dg = deg[i];
    float acc = 0.f;
    int q = 0;
    for (; q + 2 <= dg; q += 2) {
        int s0 = payload[b + q], s1 = payload[b + q + 1];
        float v0 = (s0 < n_items) ? items[(size_t)s0 * 64 + l]
                                  : user[(size_t)(s0 - n_items) * 64 + l];
        float v1 = (s1 < n_items) ? items[(size_t)s1 * 64 + l]
                                  : user[(size_t)(s1 - n_items) * 64 + l];
        acc += v0 + v1;
    }
    if (q < dg) {
        int s0 = payload[b + q];
        acc += (s0 < n_items) ? items[(size_t)s0 * 64 + l]
                              : user[(size_t)(s0 - n_items) * 64 + l];
    }
    out_u[(size_t)i * 64 + l] = acc / fmaxf((float)dg, 1.f);
}

// wave-per-item gather: icf = norm[i] * (sum_e f_e * cat[src_e]) / max(deg,1)
__global__ void ui_gather_k(const float* __restrict__ items, const float* __restrict__ user,
                            const float* __restrict__ normv,
                            const int* __restrict__ deg, const int* __restrict__ base,
                            const float2* __restrict__ payload,
                            float* __restrict__ icf, int n_items, int n) {
    int i = blockIdx.x * (blockDim.x >> 6) + (threadIdx.x >> 6);
    if (i >= n) return;
    int l = threadIdx.x & 63;
    int b = base[i], dg = deg[i];
    float acc = 0.f;
    int q = 0;
    for (; q + 2 <= dg; q += 2) {
        float2 p0 = payload[b + q], p1 = payload[b + q + 1];
        int s0 = __float_as_int(p0.x), s1 = __float_as_int(p1.x);
        float v0 = (s0 < n_items) ? items[(size_t)s0 * 64 + l]
                                  : user[(size_t)(s0 - n_items) * 64 + l];
        float v1 = (s1 < n_items) ? items[(size_t)s1 * 64 + l]
                                  : user[(size_t)(s1 - n_items) * 64 + l];
        acc += p0.y * v0 + p1.y * v1;
    }
    if (q < dg) {
        float2 p0 = payload[b + q];
        int s0 = __float_as_int(p0.x);
        acc += p0.y * ((s0 < n_items) ? items[(size_t)s0 * 64 + l]
                                      : user[(size_t)(s0 - n_items) * 64 + l]);
    }
    icf[(size_t)i * 64 + l] = normv[i] * acc / fmaxf((float)dg, 1.f);
}

// gate + fusion: gi = sigmoid(oi@W1.T + icf@W2.T); out = gi*oi + (1-gi)*icf
__global__ __launch_bounds__(256) void fusion_k(const float* __restrict__ items,
                         const float* __restrict__ icf,
                         const float* __restrict__ W1, const float* __restrict__ W2,
                         float* __restrict__ outf, int n_items) {
    __shared__ float W1s[64][65];
    __shared__ float W2s[64][65];
    for (int idx = threadIdx.x; idx < 4096; idx += blockDim.x) {
        W1s[idx >> 6][idx & 63] = W1[idx];
        W2s[idx >> 6][idx & 63] = W2[idx];
    }
    __syncthreads();
    int i = blockIdx.x * (blockDim.x >> 6) + (threadIdx.x >> 6);
    if (i >= n_items) return;
    int j = threadIdx.x & 63;
    float oi = items[(size_t)i * 64 + j];
    float cf = icf[(size_t)i * 64 + j];
    float acc = 0.f;
#pragma unroll 8
    for (int k = 0; k < 64; ++k) {
        acc += __shfl(oi, k) * W1s[j][k] + __shfl(cf, k) * W2s[j][k];
    }
    float g = 1.f / (1.f + expf(-acc));
    outf[(size_t)i * 64 + j] = g * oi + (1.f - g) * cf;
}

extern "C" void kernel_launch(void* const* d_in, const int* in_sizes, int n_in,
                              void* d_out, int out_size, void* d_ws, size_t ws_size,
                              hipStream_t stream) {
    const float* ent    = (const float*)d_in[0];
    const float* usr    = (const float*)d_in[1];
    const float* rel    = (const float*)d_in[2];
    const float* W1     = (const float*)d_in[3];
    const float* W2     = (const float*)d_in[4];
    const int*   kg_src = (const int*)d_in[5];
    const int*   kg_dst = (const int*)d_in[6];
    const int*   kg_typ = (const int*)d_in[7];
    const int*   iu_src = (const int*)d_in[8];
    const int*   iu_dst = (const int*)d_in[9];
    const int*   ui_src = (const int*)d_in[10];
    const int*   ui_dst = (const int*)d_in[11];

    const int n_ent   = in_sizes[0] / 64;
    const int n_usr   = in_sizes[1] / 64;
    const int E_kg    = in_sizes[5];
    const int E_iu    = in_sizes[8];
    const int E_ui    = in_sizes[10];
    const int n_items = (out_size - in_sizes[0] - in_sizes[1]) / 64;
    const int N       = n_items + n_usr;

    float* out_final = (float*)d_out;                        // (n_ent,64)
    float* out_u     = out_final + (size_t)n_ent * 64;       // (n_usr,64)
    float* out_items = out_u + (size_t)n_usr * 64;           // (n_items,64)

    // dots scratch lives in d_out's entity chunk: 24B/edge (19.2MB < 25.6MB).
    float4* dotsA = (float4*)d_out;                          // E_kg * 16B
    float2* dotsB = (float2*)((float*)d_out + (size_t)E_kg * 4); // E_kg * 8B

    float* ws = (float*)d_ws;
    size_t o = 0;
    // --- contiguous histogram block (single memset) ---
    int*   deg_e = (int*)(ws + o);  size_t hist0 = o; o += n_ent;
    int*   gt_e  = (int*)(ws + o);  o += 1;
    int*   deg_u = (int*)(ws + o);  o += n_usr;
    int*   gt_u  = (int*)(ws + o);  o += 1;
    int*   deg_i = (int*)(ws + o);  o += n_items;
    int*   gt_i  = (int*)(ws + o);  o += 1;
    size_t hist_len = ((size_t)(n_ent + n_usr + n_items) + 3) * sizeof(int);
    // --- bases/cursors (written by alloc, no zeroing) ---
    int*   base_e = (int*)(ws + o); o += n_ent;
    int*   cur_e  = (int*)(ws + o); o += n_ent;
    int*   base_u = (int*)(ws + o); o += n_usr;
    int*   cur_u  = (int*)(ws + o); o += n_usr;
    int*   base_i = (int*)(ws + o); o += n_items;
    int*   cur_i  = (int*)(ws + o); o += n_items;
    o = (o + 3) & ~(size_t)3;                      // 16B align
    float4* pay_kg = (float4*)(ws + o); o += (size_t)E_kg * 4;
    int*    pay_iu = (int*)(ws + o);    o += E_iu;
    o = (o + 1) & ~(size_t)1;                      // 8B align
    float2* pay_ui = (float2*)(ws + o); o += (size_t)E_ui * 2;
    float* normv = ws + o;          o += N;
    float* icf   = ws + o;          o += (size_t)n_items * 64;

    hipMemsetAsync(deg_e, 0, hist_len, stream);

    // KG CSR build + compute
    hist_k<<<(E_kg + 255) / 256, 256, 0, stream>>>(kg_src, deg_e, 0, n_ent, E_kg);
    alloc_k<<<(n_ent + 255) / 256, 256, 0, stream>>>(deg_e, base_e, cur_e, gt_e, n_ent);
    kg_dots_k<<<(E_kg + 63) / 64, 256, 0, stream>>>(ent, rel, kg_src, kg_dst, kg_typ,
                                                    dotsA, dotsB, E_kg);
    kg_chain_k<<<(E_kg + 255) / 256, 256, 0, stream>>>(dotsA, dotsB, kg_src, kg_dst,
                                                       kg_typ, cur_e, pay_kg, E_kg);
    kg_gather_k<<<(n_ent + 3) / 4, 256, 0, stream>>>(ent, rel, deg_e, base_e, pay_kg,
                                                     out_final, out_items, n_items, n_ent);

    // norms over cat_nodes
    norm_k<<<(N + 3) / 4, 256, 0, stream>>>(out_items, usr, normv, n_items, N);

    // CF CSR builds
    hist_k<<<(E_iu + 255) / 256, 256, 0, stream>>>(iu_dst, deg_u, n_items, N, E_iu);
    alloc_k<<<(n_usr + 255) / 256, 256, 0, stream>>>(deg_u, base_u, cur_u, gt_u, n_usr);
    iu_scat_k<<<(E_iu + 255) / 256, 256, 0, stream>>>(iu_src, iu_dst, cur_u, pay_iu,
                                                      n_items, N, E_iu);
    hist_k<<<(E_ui + 255) / 256, 256, 0, stream>>>(ui_dst, deg_i, 0, n_items, E_ui);
    alloc_k<<<(n_items + 255) / 256, 256, 0, stream>>>(deg_i, base_i, cur_i, gt_i, n_items);
    ui_scat_k<<<(E_ui + 255) / 256, 256, 0, stream>>>(ui_src, ui_dst, normv, cur_i,
                                                      pay_ui, n_items, E_ui);

    // CF gathers (direct output writes)
    iu_gather_k<<<(n_usr + 3) / 4, 256, 0, stream>>>(out_items, usr, deg_u, base_u,
                                                     pay_iu, out_u, n_items, n_usr);
    ui_gather_k<<<(n_items + 3) / 4, 256, 0, stream>>>(out_items, usr, normv, deg_i,
                                                       base_i, pay_ui, icf, n_items,
                                                       n_items);
    fusion_k<<<(n_items + 3) / 4, 256, 0, stream>>>(out_items, icf, W1, W2,
                                                    out_final, n_items);
}

// Round 7
// 454.423 us; speedup vs baseline: 1.8015x; 1.1400x over previous
//
#include <hip/hip_runtime.h>
#include <cstdint>

#define EPSF 1e-15f
#define MAXN (1.0f - 1e-5f)

typedef __attribute__((ext_vector_type(8))) short bf16x8;
typedef __attribute__((ext_vector_type(4))) float f32x4;

__device__ __forceinline__ float wsum64(float v) {
    v += __shfl_xor(v, 1);
    v += __shfl_xor(v, 2);
    v += __shfl_xor(v, 4);
    v += __shfl_xor(v, 8);
    v += __shfl_xor(v, 16);
    v += __shfl_xor(v, 32);
    return v;
}

__device__ __forceinline__ float dot4(float4 a, float4 b) {
    return a.x * b.x + a.y * b.y + a.z * b.z + a.w * b.w;
}

__device__ __forceinline__ short f2bf(float f) {
    uint32_t b = __float_as_uint(f);
    b = (b + 0x7FFF + ((b >> 16) & 1)) >> 16;
    return (short)b;
}

// pack 8 consecutive floats at p into a bf16x8 fragment
__device__ __forceinline__ bf16x8 pack8(const float* __restrict__ p) {
    float4 lo = *(const float4*)p;
    float4 hi = *(const float4*)(p + 4);
    bf16x8 r;
    r[0] = f2bf(lo.x); r[1] = f2bf(lo.y); r[2] = f2bf(lo.z); r[3] = f2bf(lo.w);
    r[4] = f2bf(hi.x); r[5] = f2bf(hi.y); r[6] = f2bf(hi.z); r[7] = f2bf(hi.w);
    return r;
}

// generic degree histogram with range filter: idx in [lo,hi) -> deg[idx-lo]++
__global__ void hist_k(const int* __restrict__ idx, int* __restrict__ deg,
                       int lo, int hi, int nE) {
    int e = blockIdx.x * blockDim.x + threadIdx.x;
    if (e >= nE) return;
    int d = idx[e];
    if (d >= lo && d < hi) atomicAdd(&deg[d - lo], 1);
}

// contiguous segment allocation via atomic offset (order-free CSR)
__global__ void alloc_k(const int* __restrict__ deg, int* __restrict__ base,
                        int* __restrict__ cursor, int* __restrict__ gtotal, int n) {
    int i = blockIdx.x * blockDim.x + threadIdx.x;
    if (i < n) {
        int b = atomicAdd(gtotal, deg[i]);
        base[i] = b;
        cursor[i] = b;
    }
}

// ---------------- KG path ----------------

// Gram-dots kernel: 4 lanes per edge; lane j0 reads float4 (4i+j0) so each
// load instruction consumes whole 64B lines. 2-step shfl reduce.
__global__ __launch_bounds__(256) void kg_dots_k(const float* __restrict__ ent,
                          const float* __restrict__ rel,
                          const int* __restrict__ src,
                          const int* __restrict__ dst,
                          const int* __restrict__ typ,
                          float4* __restrict__ dotsA,
                          float2* __restrict__ dotsB,
                          int nE) {
    int w = blockIdx.x * 4 + (threadIdx.x >> 6);
    int l = threadIdx.x & 63;
    int e = w * 16 + (l >> 2);
    if (e >= nE) return;
    int j0 = l & 3;
    const float4* pu = (const float4*)(ent + (size_t)src[e] * 64);
    const float4* pv = (const float4*)(ent + (size_t)dst[e] * 64);
    const float4* pr = (const float4*)(rel + (size_t)(typ[e] + 2) * 64);

    float uu = 0.f, vv = 0.f, rr = 0.f, uv = 0.f, ur = 0.f, vr = 0.f;
#pragma unroll
    for (int i = 0; i < 4; ++i) {
        float4 a = pu[4 * i + j0], b = pv[4 * i + j0], c = pr[4 * i + j0];
        uu += dot4(a, a); vv += dot4(b, b); rr += dot4(c, c);
        uv += dot4(a, b); ur += dot4(a, c); vr += dot4(b, c);
    }
#pragma unroll
    for (int m = 1; m < 4; m <<= 1) {
        uu += __shfl_xor(uu, m);
        vv += __shfl_xor(vv, m);
        rr += __shfl_xor(rr, m);
        uv += __shfl_xor(uv, m);
        ur += __shfl_xor(ur, m);
        vr += __shfl_xor(vr, m);
    }
    if (j0 == 0) dotsA[e] = make_float4(uu, vv, rr, uv);
    if (j0 == 1) dotsB[e] = make_float2(ur, vr);
}

// Chain kernel: thread-per-edge, scalar hyperbolic chain run ONCE per edge.
// payload = {b, c, a, pack(dst,typ)} at CSR slot of src.
__global__ __launch_bounds__(256) void kg_chain_k(const float4* __restrict__ dotsA,
                           const float2* __restrict__ dotsB,
                           const int* __restrict__ src,
                           const int* __restrict__ dst,
                           const int* __restrict__ typ,
                           int* __restrict__ cursor,
                           float4* __restrict__ payload,
                           int nE) {
    int e = blockIdx.x * blockDim.x + threadIdx.x;
    if (e >= nE) return;
    float4 dA = dotsA[e];
    float2 dB = dotsB[e];
    float uu = dA.x, vv = dA.y, rr = dA.z, uv = dA.w, ur = dB.x, vr = dB.y;
    int s = src[e], d = dst[e], ty = typ[e] + 2;

    float n0 = sqrtf(fmaxf(uu, EPSF));
    float cp = tanhf(n0) / n0;
    float p2 = cp * cp * uu;
    float om_p2 = 1.f - p2;
    float lam = 2.f / fmaxf(om_p2, EPSF);

    float nv = sqrtf(fmaxf(vv, EPSF));
    float cd = tanhf(0.5f * lam * nv) / nv;
    float wd2 = cd * cd * vv;
    float pwd = cp * cd * uv;
    float Dd = fmaxf(1.f + 2.f * pwd + p2 * wd2, EPSF);
    float a1 = (1.f + 2.f * pwd + wd2) * cp / Dd;
    float b1 = om_p2 * cd / Dd;

    float nr = sqrtf(fmaxf(rr, EPSF));
    float cr = tanhf(0.5f * lam * nr) / nr;
    float wr2 = cr * cr * rr;
    float pwr = cp * cr * ur;
    float Dr = fmaxf(1.f + 2.f * pwr + p2 * wr2, EPSF);
    float a2 = (1.f + 2.f * pwr + wr2) * cp / Dr;
    float c2 = om_p2 * cr / Dr;

    float x2 = a1 * a1 * uu + 2.f * a1 * b1 * uv + b1 * b1 * vv;
    float y2 = a2 * a2 * uu + 2.f * a2 * c2 * ur + c2 * c2 * rr;
    float xy = a1 * a2 * uu + a1 * c2 * ur + b1 * a2 * uv + b1 * c2 * vr;
    float den = fmaxf(1.f + 2.f * xy + x2 * y2, EPSF);
    float E = (1.f + 2.f * xy + y2) / den;
    float F = (1.f - x2) / den;
    float zu = E * a1 + F * a2;
    float zv = E * b1;
    float zr = F * c2;

    float z2 = zu * zu * uu + zv * zv * vv + zr * zr * rr
             + 2.f * (zu * zv * uv + zu * zr * ur + zv * zr * vr);
    float nz = sqrtf(fmaxf(z2, EPSF));
    if (nz > MAXN) {
        float sc = MAXN / nz;
        zu *= sc; zv *= sc; zr *= sc;
        z2 *= sc * sc;
    }

    float mxy = -cp * (zu * uu + zv * uv + zr * ur);
    float denl = fmaxf(1.f + 2.f * mxy + p2 * z2, EPSF);
    float G = (1.f + 2.f * mxy + z2) / denl;
    float H = om_p2 / denl;
    float su = -G * cp + H * zu;
    float sv = H * zv;
    float sr = H * zr;

    float ns2 = su * su * uu + sv * sv * vv + sr * sr * rr
              + 2.f * (su * sv * uv + su * sr * ur + sv * sr * vr);
    float ns = sqrtf(fmaxf(ns2, EPSF));
    float k = fmaxf(om_p2, EPSF) * atanhf(fminf(ns, MAXN)) / ns;

    int pos = atomicAdd(&cursor[s], 1);
    payload[pos] = make_float4(k * sv, k * sr, k * su,
                               __int_as_float(d | (ty << 18)));
}

// Wave-per-entity CSR gather, 4x unrolled: out = (sum b*v + c*r + (sum a)*u)/deg
__global__ void kg_gather_k(const float* __restrict__ ent,
                            const float* __restrict__ rel,
                            const int* __restrict__ deg,
                            const int* __restrict__ base,
                            const float4* __restrict__ payload,
                            float* __restrict__ out_final,
                            float* __restrict__ out_items,
                            int n_items, int n) {
    int i = blockIdx.x * (blockDim.x >> 6) + (threadIdx.x >> 6);
    if (i >= n) return;
    int l = threadIdx.x & 63;
    int b = base[i], dg = deg[i];
    float acc = 0.f, as = 0.f;
    int q = 0;
    for (; q + 4 <= dg; q += 4) {
        float4 p0 = payload[b + q];
        float4 p1 = payload[b + q + 1];
        float4 p2 = payload[b + q + 2];
        float4 p3 = payload[b + q + 3];
        int w0 = __float_as_int(p0.w), w1 = __float_as_int(p1.w);
        int w2 = __float_as_int(p2.w), w3 = __float_as_int(p3.w);
        float v0 = ent[(size_t)(w0 & 0x3FFFF) * 64 + l];
        float r0 = rel[(size_t)(w0 >> 18) * 64 + l];
        float v1 = ent[(size_t)(w1 & 0x3FFFF) * 64 + l];
        float r1 = rel[(size_t)(w1 >> 18) * 64 + l];
        float v2 = ent[(size_t)(w2 & 0x3FFFF) * 64 + l];
        float r2 = rel[(size_t)(w2 >> 18) * 64 + l];
        float v3 = ent[(size_t)(w3 & 0x3FFFF) * 64 + l];
        float r3 = rel[(size_t)(w3 >> 18) * 64 + l];
        acc += p0.x * v0 + p0.y * r0 + p1.x * v1 + p1.y * r1;
        acc += p2.x * v2 + p2.y * r2 + p3.x * v3 + p3.y * r3;
        as += (p0.z + p1.z) + (p2.z + p3.z);
    }
    for (; q < dg; ++q) {
        float4 p = payload[b + q];
        int w = __float_as_int(p.w);
        acc += p.x * ent[(size_t)(w & 0x3FFFF) * 64 + l]
             + p.y * rel[(size_t)(w >> 18) * 64 + l];
        as += p.z;
    }
    float v = (acc + as * ent[(size_t)i * 64 + l]) / fmaxf((float)dg, 1.f);
    if (i < n_items) out_items[(size_t)i * 64 + l] = v;
    else             out_final[(size_t)i * 64 + l] = v;
}

// ---------------- CF path ----------------

// norm_all[j] = sum_d cat_nodes[j,d]^2 ; wave per node
__global__ void norm_k(const float* __restrict__ items, const float* __restrict__ user,
                       float* __restrict__ normv, int n_items, int N) {
    int j = blockIdx.x * (blockDim.x >> 6) + (threadIdx.x >> 6);
    if (j >= N) return;
    int l = threadIdx.x & 63;
    float c = (j < n_items) ? items[(size_t)j * 64 + l]
                            : user[(size_t)(j - n_items) * 64 + l];
    float s = wsum64(c * c);
    if (l == 0) normv[j] = s;
}

// iu scatter: payload = src index at CSR slot of (dst - n_items)
__global__ void iu_scat_k(const int* __restrict__ srcA, const int* __restrict__ dstA,
                          int* __restrict__ cursor, int* __restrict__ payload,
                          int n_items, int N, int nE) {
    int e = blockIdx.x * blockDim.x + threadIdx.x;
    if (e >= nE) return;
    int d = dstA[e];
    if (d < n_items || d >= N) return;
    int pos = atomicAdd(&cursor[d - n_items], 1);
    payload[pos] = srcA[e];
}

// ui scatter: payload = {src, 1/(norm[src]+1e-6)} at CSR slot of dst
__global__ void ui_scat_k(const int* __restrict__ srcA, const int* __restrict__ dstA,
                          const float* __restrict__ normv,
                          int* __restrict__ cursor, float2* __restrict__ payload,
                          int n_items, int nE) {
    int e = blockIdx.x * blockDim.x + threadIdx.x;
    if (e >= nE) return;
    int d = dstA[e];
    if (d >= n_items) return;
    int s = srcA[e];
    int pos = atomicAdd(&cursor[d], 1);
    payload[pos] = make_float2(__int_as_float(s), 1.f / (normv[s] + 1e-6f));
}

// wave-per-user gather, 4x unrolled: out_u = (sum cat[src]) / deg, direct write
__global__ void iu_gather_k(const float* __restrict__ items, const float* __restrict__ user,
                            const int* __restrict__ deg, const int* __restrict__ base,
                            const int* __restrict__ payload,
                            float* __restrict__ out_u, int n_items, int n) {
    int i = blockIdx.x * (blockDim.x >> 6) + (threadIdx.x >> 6);
    if (i >= n) return;
    int l = threadIdx.x & 63;
    int b = base[i], dg = deg[i];
    float acc = 0.f;
    int q = 0;
    for (; q + 4 <= dg; q += 4) {
        int s0 = payload[b + q], s1 = payload[b + q + 1];
        int s2 = payload[b + q + 2], s3 = payload[b + q + 3];
        float v0 = (s0 < n_items) ? items[(size_t)s0 * 64 + l]
                                  : user[(size_t)(s0 - n_items) * 64 + l];
        float v1 = (s1 < n_items) ? items[(size_t)s1 * 64 + l]
                                  : user[(size_t)(s1 - n_items) * 64 + l];
        float v2 = (s2 < n_items) ? items[(size_t)s2 * 64 + l]
                                  : user[(size_t)(s2 - n_items) * 64 + l];
        float v3 = (s3 < n_items) ? items[(size_t)s3 * 64 + l]
                                  : user[(size_t)(s3 - n_items) * 64 + l];
        acc += (v0 + v1) + (v2 + v3);
    }
    for (; q < dg; ++q) {
        int s0 = payload[b + q];
        acc += (s0 < n_items) ? items[(size_t)s0 * 64 + l]
                              : user[(size_t)(s0 - n_items) * 64 + l];
    }
    out_u[(size_t)i * 64 + l] = acc / fmaxf((float)dg, 1.f);
}

// wave-per-item gather, 4x unrolled: icf = norm[i]*(sum f_e*cat[src_e])/deg
__global__ void ui_gather_k(const float* __restrict__ items, const float* __restrict__ user,
                            const float* __restrict__ normv,
                            const int* __restrict__ deg, const int* __restrict__ base,
                            const float2* __restrict__ payload,
                            float* __restrict__ icf, int n_items, int n) {
    int i = blockIdx.x * (blockDim.x >> 6) + (threadIdx.x >> 6);
    if (i >= n) return;
    int l = threadIdx.x & 63;
    int b = base[i], dg = deg[i];
    float acc = 0.f;
    int q = 0;
    for (; q + 4 <= dg; q += 4) {
        float2 p0 = payload[b + q], p1 = payload[b + q + 1];
        float2 p2 = payload[b + q + 2], p3 = payload[b + q + 3];
        int s0 = __float_as_int(p0.x), s1 = __float_as_int(p1.x);
        int s2 = __float_as_int(p2.x), s3 = __float_as_int(p3.x);
        float v0 = (s0 < n_items) ? items[(size_t)s0 * 64 + l]
                                  : user[(size_t)(s0 - n_items) * 64 + l];
        float v1 = (s1 < n_items) ? items[(size_t)s1 * 64 + l]
                                  : user[(size_t)(s1 - n_items) * 64 + l];
        float v2 = (s2 < n_items) ? items[(size_t)s2 * 64 + l]
                                  : user[(size_t)(s2 - n_items) * 64 + l];
        float v3 = (s3 < n_items) ? items[(size_t)s3 * 64 + l]
                                  : user[(size_t)(s3 - n_items) * 64 + l];
        acc += (p0.y * v0 + p1.y * v1) + (p2.y * v2 + p3.y * v3);
    }
    for (; q < dg; ++q) {
        float2 p0 = payload[b + q];
        int s0 = __float_as_int(p0.x);
        acc += p0.y * ((s0 < n_items) ? items[(size_t)s0 * 64 + l]
                                      : user[(size_t)(s0 - n_items) * 64 + l]);
    }
    icf[(size_t)i * 64 + l] = normv[i] * acc / fmaxf((float)dg, 1.f);
}

// MFMA gate+fusion: acc = [oi|cf] @ [W1;W2]^T (bf16), out = g*oi + (1-g)*cf.
// Block = 4 waves x 16-row tiles = 64 rows. Per wave: 4 col-tiles x 4 k-steps.
// A/B frags: row/col = lane&15, k = (lane>>4)*8 + e (symmetric bijection).
// C/D: col = lane&15, row = (lane>>4)*4 + reg (measured layout).
__global__ __launch_bounds__(256) void fusion_mfma_k(const float* __restrict__ items,
                          const float* __restrict__ icf,
                          const float* __restrict__ W1, const float* __restrict__ W2,
                          float* __restrict__ outf, int n_items) {
    int lane = threadIdx.x & 63;
    int row0 = blockIdx.x * 64 + (threadIdx.x >> 6) * 16;
    int r = lane & 15, g = lane >> 4;

    int arow = row0 + r;
    size_t rbase = (size_t)(arow < n_items ? arow : 0) * 64;

    bf16x8 afrag[4];
#pragma unroll
    for (int s = 0; s < 4; ++s) {
        int kb = s * 32 + g * 8;
        const float* p = (kb < 64) ? (items + rbase + kb) : (icf + rbase + kb - 64);
        afrag[s] = pack8(p);
    }

    bf16x8 bfrag[4][4];
#pragma unroll
    for (int c = 0; c < 4; ++c) {
        int col = c * 16 + r;
#pragma unroll
        for (int s = 0; s < 4; ++s) {
            int kb = s * 32 + g * 8;
            const float* p = (kb < 64) ? (W1 + col * 64 + kb) : (W2 + col * 64 + kb - 64);
            bfrag[c][s] = pack8(p);
        }
    }

    f32x4 acc[4] = {{0.f,0.f,0.f,0.f},{0.f,0.f,0.f,0.f},
                    {0.f,0.f,0.f,0.f},{0.f,0.f,0.f,0.f}};
#pragma unroll
    for (int s = 0; s < 4; ++s)
#pragma unroll
        for (int c = 0; c < 4; ++c)
            acc[c] = __builtin_amdgcn_mfma_f32_16x16x32_bf16(afrag[s], bfrag[c][s],
                                                             acc[c], 0, 0, 0);

#pragma unroll
    for (int c = 0; c < 4; ++c) {
        int col = c * 16 + r;
#pragma unroll
        for (int q = 0; q < 4; ++q) {
            int orow = row0 + g * 4 + q;
            if (orow < n_items) {
                size_t off = (size_t)orow * 64 + col;
                float oi = items[off], cf = icf[off];
                float gate = 1.f / (1.f + expf(-acc[c][q]));
                outf[off] = gate * oi + (1.f - gate) * cf;
            }
        }
    }
}

extern "C" void kernel_launch(void* const* d_in, const int* in_sizes, int n_in,
                              void* d_out, int out_size, void* d_ws, size_t ws_size,
                              hipStream_t stream) {
    const float* ent    = (const float*)d_in[0];
    const float* usr    = (const float*)d_in[1];
    const float* rel    = (const float*)d_in[2];
    const float* W1     = (const float*)d_in[3];
    const float* W2     = (const float*)d_in[4];
    const int*   kg_src = (const int*)d_in[5];
    const int*   kg_dst = (const int*)d_in[6];
    const int*   kg_typ = (const int*)d_in[7];
    const int*   iu_src = (const int*)d_in[8];
    const int*   iu_dst = (const int*)d_in[9];
    const int*   ui_src = (const int*)d_in[10];
    const int*   ui_dst = (const int*)d_in[11];

    const int n_ent   = in_sizes[0] / 64;
    const int n_usr   = in_sizes[1] / 64;
    const int E_kg    = in_sizes[5];
    const int E_iu    = in_sizes[8];
    const int E_ui    = in_sizes[10];
    const int n_items = (out_size - in_sizes[0] - in_sizes[1]) / 64;
    const int N       = n_items + n_usr;

    float* out_final = (float*)d_out;                        // (n_ent,64)
    float* out_u     = out_final + (size_t)n_ent * 64;       // (n_usr,64)
    float* out_items = out_u + (size_t)n_usr * 64;           // (n_items,64)

    // dots scratch lives in d_out's entity chunk: 24B/edge (19.2MB < 25.6MB).
    float4* dotsA = (float4*)d_out;                          // E_kg * 16B
    float2* dotsB = (float2*)((float*)d_out + (size_t)E_kg * 4); // E_kg * 8B

    float* ws = (float*)d_ws;
    size_t o = 0;
    // --- contiguous histogram block (single memset) ---
    int*   deg_e = (int*)(ws + o);  o += n_ent;
    int*   gt_e  = (int*)(ws + o);  o += 1;
    int*   deg_u = (int*)(ws + o);  o += n_usr;
    int*   gt_u  = (int*)(ws + o);  o += 1;
    int*   deg_i = (int*)(ws + o);  o += n_items;
    int*   gt_i  = (int*)(ws + o);  o += 1;
    size_t hist_len = ((size_t)(n_ent + n_usr + n_items) + 3) * sizeof(int);
    // --- bases/cursors (written by alloc, no zeroing) ---
    int*   base_e = (int*)(ws + o); o += n_ent;
    int*   cur_e  = (int*)(ws + o); o += n_ent;
    int*   base_u = (int*)(ws + o); o += n_usr;
    int*   cur_u  = (int*)(ws + o); o += n_usr;
    int*   base_i = (int*)(ws + o); o += n_items;
    int*   cur_i  = (int*)(ws + o); o += n_items;
    o = (o + 3) & ~(size_t)3;                      // 16B align
    float4* pay_kg = (float4*)(ws + o); o += (size_t)E_kg * 4;
    int*    pay_iu = (int*)(ws + o);    o += E_iu;
    o = (o + 1) & ~(size_t)1;                      // 8B align
    float2* pay_ui = (float2*)(ws + o); o += (size_t)E_ui * 2;
    float* normv = ws + o;          o += N;
    o = (o + 3) & ~(size_t)3;                      // 16B align for float4 reads
    float* icf   = ws + o;          o += (size_t)n_items * 64;

    hipMemsetAsync(deg_e, 0, hist_len, stream);

    // KG CSR build + compute
    hist_k<<<(E_kg + 255) / 256, 256, 0, stream>>>(kg_src, deg_e, 0, n_ent, E_kg);
    alloc_k<<<(n_ent + 255) / 256, 256, 0, stream>>>(deg_e, base_e, cur_e, gt_e, n_ent);
    kg_dots_k<<<(E_kg + 63) / 64, 256, 0, stream>>>(ent, rel, kg_src, kg_dst, kg_typ,
                                                    dotsA, dotsB, E_kg);
    kg_chain_k<<<(E_kg + 255) / 256, 256, 0, stream>>>(dotsA, dotsB, kg_src, kg_dst,
                                                       kg_typ, cur_e, pay_kg, E_kg);
    kg_gather_k<<<(n_ent + 3) / 4, 256, 0, stream>>>(ent, rel, deg_e, base_e, pay_kg,
                                                     out_final, out_items, n_items, n_ent);

    // norms over cat_nodes
    norm_k<<<(N + 3) / 4, 256, 0, stream>>>(out_items, usr, normv, n_items, N);

    // CF CSR builds
    hist_k<<<(E_iu + 255) / 256, 256, 0, stream>>>(iu_dst, deg_u, n_items, N, E_iu);
    alloc_k<<<(n_usr + 255) / 256, 256, 0, stream>>>(deg_u, base_u, cur_u, gt_u, n_usr);
    iu_scat_k<<<(E_iu + 255) / 256, 256, 0, stream>>>(iu_src, iu_dst, cur_u, pay_iu,
                                                      n_items, N, E_iu);
    hist_k<<<(E_ui + 255) / 256, 256, 0, stream>>>(ui_dst, deg_i, 0, n_items, E_ui);
    alloc_k<<<(n_items + 255) / 256, 256, 0, stream>>>(deg_i, base_i, cur_i, gt_i, n_items);
    ui_scat_k<<<(E_ui + 255) / 256, 256, 0, stream>>>(ui_src, ui_dst, normv, cur_i,
                                                      pay_ui, n_items, E_ui);

    // CF gathers (direct output writes)
    iu_gather_k<<<(n_usr + 3) / 4, 256, 0, stream>>>(out_items, usr, deg_u, base_u,
                                                     pay_iu, out_u, n_items, n_usr);
    ui_gather_k<<<(n_items + 3) / 4, 256, 0, stream>>>(out_items, usr, normv, deg_i,
                                                       base_i, pay_ui, icf, n_items,
                                                       n_items);
    fusion_mfma_k<<<(n_items + 63) / 64, 256, 0, stream>>>(out_items, icf, W1, W2,
                                                           out_final, n_items);
}

// Round 8
// 385.596 us; speedup vs baseline: 2.1230x; 1.1785x over previous
//
#include <hip/hip_runtime.h>
#include <cstdint>

#define EPSF 1e-15f
#define MAXN (1.0f - 1e-5f)

typedef __attribute__((ext_vector_type(8))) short bf16x8;
typedef __attribute__((ext_vector_type(4))) float f32x4;

__device__ __forceinline__ float wsum64(float v) {
    v += __shfl_xor(v, 1);
    v += __shfl_xor(v, 2);
    v += __shfl_xor(v, 4);
    v += __shfl_xor(v, 8);
    v += __shfl_xor(v, 16);
    v += __shfl_xor(v, 32);
    return v;
}

__device__ __forceinline__ float dot4(float4 a, float4 b) {
    return a.x * b.x + a.y * b.y + a.z * b.z + a.w * b.w;
}

__device__ __forceinline__ short f2bf(float f) {
    uint32_t b = __float_as_uint(f);
    b = (b + 0x7FFF + ((b >> 16) & 1)) >> 16;
    return (short)b;
}

__device__ __forceinline__ bf16x8 pack8(const float* __restrict__ p) {
    float4 lo = *(const float4*)p;
    float4 hi = *(const float4*)(p + 4);
    bf16x8 r;
    r[0] = f2bf(lo.x); r[1] = f2bf(lo.y); r[2] = f2bf(lo.z); r[3] = f2bf(lo.w);
    r[4] = f2bf(hi.x); r[5] = f2bf(hi.y); r[6] = f2bf(hi.z); r[7] = f2bf(hi.w);
    return r;
}

// combined histogram for all three graphs (one launch)
__global__ void hist3_k(const int* __restrict__ kg_src, const int* __restrict__ iu_dst,
                        const int* __restrict__ ui_dst,
                        int* __restrict__ deg_e, int* __restrict__ deg_u,
                        int* __restrict__ deg_i,
                        int E_kg, int E_iu, int E_ui, int n_items, int N) {
    int t = blockIdx.x * blockDim.x + threadIdx.x;
    if (t < E_kg) { atomicAdd(&deg_e[kg_src[t]], 1); return; }
    t -= E_kg;
    if (t < E_iu) {
        int d = iu_dst[t];
        if (d >= n_items && d < N) atomicAdd(&deg_u[d - n_items], 1);
        return;
    }
    t -= E_iu;
    if (t < E_ui) {
        int d = ui_dst[t];
        if (d < n_items) atomicAdd(&deg_i[d], 1);
    }
}

// combined CSR segment allocation for all three graphs (one launch)
__global__ void alloc3_k(const int* __restrict__ deg_e, const int* __restrict__ deg_u,
                         const int* __restrict__ deg_i,
                         int* __restrict__ base_e, int* __restrict__ cur_e,
                         int* __restrict__ base_u, int* __restrict__ cur_u,
                         int* __restrict__ base_i, int* __restrict__ cur_i,
                         int* __restrict__ gt_e, int* __restrict__ gt_u,
                         int* __restrict__ gt_i,
                         int n_ent, int n_usr, int n_items) {
    int t = blockIdx.x * blockDim.x + threadIdx.x;
    if (t < n_ent) { int b = atomicAdd(gt_e, deg_e[t]); base_e[t] = b; cur_e[t] = b; return; }
    t -= n_ent;
    if (t < n_usr) { int b = atomicAdd(gt_u, deg_u[t]); base_u[t] = b; cur_u[t] = b; return; }
    t -= n_usr;
    if (t < n_items) { int b = atomicAdd(gt_i, deg_i[t]); base_i[t] = b; cur_i[t] = b; }
}

// ---------------- KG path ----------------

// Merged dots+chain: 4 lanes/edge coalesced row reads, 2-step shfl reduce
// (all 4 lanes get the 6 Gram dots), scalar hyperbolic chain run 4x-redundant
// (free: SIMD executes the wave regardless), lane 0 scatters payload at the
// CSR slot of src. payload = {b, c, a, pack(dst,typ)}; res = a*u + b*v + c*r.
__global__ __launch_bounds__(256) void kg_edge_fused_k(const float* __restrict__ ent,
                          const float* __restrict__ rel,
                          const int* __restrict__ src,
                          const int* __restrict__ dst,
                          const int* __restrict__ typ,
                          int* __restrict__ cursor,
                          float4* __restrict__ payload,
                          int nE) {
    int w = blockIdx.x * 4 + (threadIdx.x >> 6);
    int l = threadIdx.x & 63;
    int e = w * 16 + (l >> 2);
    if (e >= nE) return;
    int j0 = l & 3;
    int s = src[e], d = dst[e], ty = typ[e] + 2;
    const float4* pu = (const float4*)(ent + (size_t)s * 64);
    const float4* pv = (const float4*)(ent + (size_t)d * 64);
    const float4* pr = (const float4*)(rel + (size_t)ty * 64);

    float uu = 0.f, vv = 0.f, rr = 0.f, uv = 0.f, ur = 0.f, vr = 0.f;
#pragma unroll
    for (int i = 0; i < 4; ++i) {
        float4 a = pu[4 * i + j0], b = pv[4 * i + j0], c = pr[4 * i + j0];
        uu += dot4(a, a); vv += dot4(b, b); rr += dot4(c, c);
        uv += dot4(a, b); ur += dot4(a, c); vr += dot4(b, c);
    }
#pragma unroll
    for (int m = 1; m < 4; m <<= 1) {
        uu += __shfl_xor(uu, m);
        vv += __shfl_xor(vv, m);
        rr += __shfl_xor(rr, m);
        uv += __shfl_xor(uv, m);
        ur += __shfl_xor(ur, m);
        vr += __shfl_xor(vr, m);
    }

    float n0 = sqrtf(fmaxf(uu, EPSF));
    float cp = tanhf(n0) / n0;
    float p2 = cp * cp * uu;
    float om_p2 = 1.f - p2;
    float lam = 2.f / fmaxf(om_p2, EPSF);

    float nv = sqrtf(fmaxf(vv, EPSF));
    float cd = tanhf(0.5f * lam * nv) / nv;
    float wd2 = cd * cd * vv;
    float pwd = cp * cd * uv;
    float Dd = fmaxf(1.f + 2.f * pwd + p2 * wd2, EPSF);
    float a1 = (1.f + 2.f * pwd + wd2) * cp / Dd;
    float b1 = om_p2 * cd / Dd;

    float nr = sqrtf(fmaxf(rr, EPSF));
    float cr = tanhf(0.5f * lam * nr) / nr;
    float wr2 = cr * cr * rr;
    float pwr = cp * cr * ur;
    float Dr = fmaxf(1.f + 2.f * pwr + p2 * wr2, EPSF);
    float a2 = (1.f + 2.f * pwr + wr2) * cp / Dr;
    float c2 = om_p2 * cr / Dr;

    float x2 = a1 * a1 * uu + 2.f * a1 * b1 * uv + b1 * b1 * vv;
    float y2 = a2 * a2 * uu + 2.f * a2 * c2 * ur + c2 * c2 * rr;
    float xy = a1 * a2 * uu + a1 * c2 * ur + b1 * a2 * uv + b1 * c2 * vr;
    float den = fmaxf(1.f + 2.f * xy + x2 * y2, EPSF);
    float E = (1.f + 2.f * xy + y2) / den;
    float F = (1.f - x2) / den;
    float zu = E * a1 + F * a2;
    float zv = E * b1;
    float zr = F * c2;

    float z2 = zu * zu * uu + zv * zv * vv + zr * zr * rr
             + 2.f * (zu * zv * uv + zu * zr * ur + zv * zr * vr);
    float nz = sqrtf(fmaxf(z2, EPSF));
    if (nz > MAXN) {
        float sc = MAXN / nz;
        zu *= sc; zv *= sc; zr *= sc;
        z2 *= sc * sc;
    }

    float mxy = -cp * (zu * uu + zv * uv + zr * ur);
    float denl = fmaxf(1.f + 2.f * mxy + p2 * z2, EPSF);
    float G = (1.f + 2.f * mxy + z2) / denl;
    float H = om_p2 / denl;
    float su = -G * cp + H * zu;
    float sv = H * zv;
    float sr = H * zr;

    float ns2 = su * su * uu + sv * sv * vv + sr * sr * rr
              + 2.f * (su * sv * uv + su * sr * ur + sv * sr * vr);
    float ns = sqrtf(fmaxf(ns2, EPSF));
    float k = fmaxf(om_p2, EPSF) * atanhf(fminf(ns, MAXN)) / ns;

    if (j0 == 0) {
        int pos = atomicAdd(&cursor[s], 1);
        payload[pos] = make_float4(k * sv, k * sr, k * su,
                                   __int_as_float(d | (ty << 18)));
    }
}

// Wave-per-entity CSR gather, 4x unrolled; also emits item-row norms.
__global__ void kg_gather_k(const float* __restrict__ ent,
                            const float* __restrict__ rel,
                            const int* __restrict__ deg,
                            const int* __restrict__ base,
                            const float4* __restrict__ payload,
                            float* __restrict__ out_final,
                            float* __restrict__ out_items,
                            float* __restrict__ normv,
                            int n_items, int n) {
    int i = blockIdx.x * (blockDim.x >> 6) + (threadIdx.x >> 6);
    if (i >= n) return;
    int l = threadIdx.x & 63;
    int b = base[i], dg = deg[i];
    float acc = 0.f, as = 0.f;
    int q = 0;
    for (; q + 4 <= dg; q += 4) {
        float4 p0 = payload[b + q];
        float4 p1 = payload[b + q + 1];
        float4 p2 = payload[b + q + 2];
        float4 p3 = payload[b + q + 3];
        int w0 = __float_as_int(p0.w), w1 = __float_as_int(p1.w);
        int w2 = __float_as_int(p2.w), w3 = __float_as_int(p3.w);
        float v0 = ent[(size_t)(w0 & 0x3FFFF) * 64 + l];
        float r0 = rel[(size_t)(w0 >> 18) * 64 + l];
        float v1 = ent[(size_t)(w1 & 0x3FFFF) * 64 + l];
        float r1 = rel[(size_t)(w1 >> 18) * 64 + l];
        float v2 = ent[(size_t)(w2 & 0x3FFFF) * 64 + l];
        float r2 = rel[(size_t)(w2 >> 18) * 64 + l];
        float v3 = ent[(size_t)(w3 & 0x3FFFF) * 64 + l];
        float r3 = rel[(size_t)(w3 >> 18) * 64 + l];
        acc += p0.x * v0 + p0.y * r0 + p1.x * v1 + p1.y * r1;
        acc += p2.x * v2 + p2.y * r2 + p3.x * v3 + p3.y * r3;
        as += (p0.z + p1.z) + (p2.z + p3.z);
    }
    for (; q < dg; ++q) {
        float4 p = payload[b + q];
        int w = __float_as_int(p.w);
        acc += p.x * ent[(size_t)(w & 0x3FFFF) * 64 + l]
             + p.y * rel[(size_t)(w >> 18) * 64 + l];
        as += p.z;
    }
    float v = (acc + as * ent[(size_t)i * 64 + l]) / fmaxf((float)dg, 1.f);
    if (i < n_items) {
        out_items[(size_t)i * 64 + l] = v;
        float s2 = wsum64(v * v);
        if (l == 0) normv[i] = s2;
    } else {
        out_final[(size_t)i * 64 + l] = v;
    }
}

// norms for the user half of cat_nodes
__global__ void user_norm_k(const float* __restrict__ user, float* __restrict__ normv,
                            int n_items, int n_usr) {
    int j = blockIdx.x * (blockDim.x >> 6) + (threadIdx.x >> 6);
    if (j >= n_usr) return;
    int l = threadIdx.x & 63;
    float c = user[(size_t)j * 64 + l];
    float s = wsum64(c * c);
    if (l == 0) normv[n_items + j] = s;
}

// ---------------- CF path ----------------

// iu scatter: payload = src index at CSR slot of (dst - n_items)
__global__ void iu_scat_k(const int* __restrict__ srcA, const int* __restrict__ dstA,
                          int* __restrict__ cursor, int* __restrict__ payload,
                          int n_items, int N, int nE) {
    int e = blockIdx.x * blockDim.x + threadIdx.x;
    if (e >= nE) return;
    int d = dstA[e];
    if (d < n_items || d >= N) return;
    int pos = atomicAdd(&cursor[d - n_items], 1);
    payload[pos] = srcA[e];
}

// ui scatter: payload = {src, 1/(norm[src]+1e-6)} at CSR slot of dst
__global__ void ui_scat_k(const int* __restrict__ srcA, const int* __restrict__ dstA,
                          const float* __restrict__ normv,
                          int* __restrict__ cursor, float2* __restrict__ payload,
                          int n_items, int nE) {
    int e = blockIdx.x * blockDim.x + threadIdx.x;
    if (e >= nE) return;
    int d = dstA[e];
    if (d >= n_items) return;
    int s = srcA[e];
    int pos = atomicAdd(&cursor[d], 1);
    payload[pos] = make_float2(__int_as_float(s), 1.f / (normv[s] + 1e-6f));
}

// wave-per-user gather, 8x unrolled: out_u = (sum cat[src]) / deg
__global__ void iu_gather_k(const float* __restrict__ items, const float* __restrict__ user,
                            const int* __restrict__ deg, const int* __restrict__ base,
                            const int* __restrict__ payload,
                            float* __restrict__ out_u, int n_items, int n) {
    int i = blockIdx.x * (blockDim.x >> 6) + (threadIdx.x >> 6);
    if (i >= n) return;
    int l = threadIdx.x & 63;
    int b = base[i], dg = deg[i];
    float acc = 0.f;
    int q = 0;
    for (; q + 8 <= dg; q += 8) {
        float vs[8];
#pragma unroll
        for (int j = 0; j < 8; ++j) {
            int s0 = payload[b + q + j];
            vs[j] = (s0 < n_items) ? items[(size_t)s0 * 64 + l]
                                   : user[(size_t)(s0 - n_items) * 64 + l];
        }
#pragma unroll
        for (int j = 0; j < 8; ++j) acc += vs[j];
    }
    for (; q < dg; ++q) {
        int s0 = payload[b + q];
        acc += (s0 < n_items) ? items[(size_t)s0 * 64 + l]
                              : user[(size_t)(s0 - n_items) * 64 + l];
    }
    out_u[(size_t)i * 64 + l] = acc / fmaxf((float)dg, 1.f);
}

// wave-per-item gather, 8x unrolled: icf = norm[i]*(sum f_e*cat[src_e])/deg
__global__ void ui_gather_k(const float* __restrict__ items, const float* __restrict__ user,
                            const float* __restrict__ normv,
                            const int* __restrict__ deg, const int* __restrict__ base,
                            const float2* __restrict__ payload,
                            float* __restrict__ icf, int n_items, int n) {
    int i = blockIdx.x * (blockDim.x >> 6) + (threadIdx.x >> 6);
    if (i >= n) return;
    int l = threadIdx.x & 63;
    int b = base[i], dg = deg[i];
    float acc = 0.f;
    int q = 0;
    for (; q + 8 <= dg; q += 8) {
        float2 ps[8];
        float vs[8];
#pragma unroll
        for (int j = 0; j < 8; ++j) ps[j] = payload[b + q + j];
#pragma unroll
        for (int j = 0; j < 8; ++j) {
            int s0 = __float_as_int(ps[j].x);
            vs[j] = (s0 < n_items) ? items[(size_t)s0 * 64 + l]
                                   : user[(size_t)(s0 - n_items) * 64 + l];
        }
#pragma unroll
        for (int j = 0; j < 8; ++j) acc += ps[j].y * vs[j];
    }
    for (; q < dg; ++q) {
        float2 p0 = payload[b + q];
        int s0 = __float_as_int(p0.x);
        acc += p0.y * ((s0 < n_items) ? items[(size_t)s0 * 64 + l]
                                      : user[(size_t)(s0 - n_items) * 64 + l]);
    }
    icf[(size_t)i * 64 + l] = normv[i] * acc / fmaxf((float)dg, 1.f);
}

// MFMA gate+fusion: acc = [oi|cf] @ [W1;W2]^T (bf16), out = g*oi + (1-g)*cf.
__global__ __launch_bounds__(256) void fusion_mfma_k(const float* __restrict__ items,
                          const float* __restrict__ icf,
                          const float* __restrict__ W1, const float* __restrict__ W2,
                          float* __restrict__ outf, int n_items) {
    int lane = threadIdx.x & 63;
    int row0 = blockIdx.x * 64 + (threadIdx.x >> 6) * 16;
    int r = lane & 15, g = lane >> 4;

    int arow = row0 + r;
    size_t rbase = (size_t)(arow < n_items ? arow : 0) * 64;

    bf16x8 afrag[4];
#pragma unroll
    for (int s = 0; s < 4; ++s) {
        int kb = s * 32 + g * 8;
        const float* p = (kb < 64) ? (items + rbase + kb) : (icf + rbase + kb - 64);
        afrag[s] = pack8(p);
    }

    bf16x8 bfrag[4][4];
#pragma unroll
    for (int c = 0; c < 4; ++c) {
        int col = c * 16 + r;
#pragma unroll
        for (int s = 0; s < 4; ++s) {
            int kb = s * 32 + g * 8;
            const float* p = (kb < 64) ? (W1 + col * 64 + kb) : (W2 + col * 64 + kb - 64);
            bfrag[c][s] = pack8(p);
        }
    }

    f32x4 acc[4] = {{0.f,0.f,0.f,0.f},{0.f,0.f,0.f,0.f},
                    {0.f,0.f,0.f,0.f},{0.f,0.f,0.f,0.f}};
#pragma unroll
    for (int s = 0; s < 4; ++s)
#pragma unroll
        for (int c = 0; c < 4; ++c)
            acc[c] = __builtin_amdgcn_mfma_f32_16x16x32_bf16(afrag[s], bfrag[c][s],
                                                             acc[c], 0, 0, 0);

#pragma unroll
    for (int c = 0; c < 4; ++c) {
        int col = c * 16 + r;
#pragma unroll
        for (int q = 0; q < 4; ++q) {
            int orow = row0 + g * 4 + q;
            if (orow < n_items) {
                size_t off = (size_t)orow * 64 + col;
                float oi = items[off], cf = icf[off];
                float gate = 1.f / (1.f + expf(-acc[c][q]));
                outf[off] = gate * oi + (1.f - gate) * cf;
            }
        }
    }
}

extern "C" void kernel_launch(void* const* d_in, const int* in_sizes, int n_in,
                              void* d_out, int out_size, void* d_ws, size_t ws_size,
                              hipStream_t stream) {
    const float* ent    = (const float*)d_in[0];
    const float* usr    = (const float*)d_in[1];
    const float* rel    = (const float*)d_in[2];
    const float* W1     = (const float*)d_in[3];
    const float* W2     = (const float*)d_in[4];
    const int*   kg_src = (const int*)d_in[5];
    const int*   kg_dst = (const int*)d_in[6];
    const int*   kg_typ = (const int*)d_in[7];
    const int*   iu_src = (const int*)d_in[8];
    const int*   iu_dst = (const int*)d_in[9];
    const int*   ui_src = (const int*)d_in[10];
    const int*   ui_dst = (const int*)d_in[11];

    const int n_ent   = in_sizes[0] / 64;
    const int n_usr   = in_sizes[1] / 64;
    const int E_kg    = in_sizes[5];
    const int E_iu    = in_sizes[8];
    const int E_ui    = in_sizes[10];
    const int n_items = (out_size - in_sizes[0] - in_sizes[1]) / 64;
    const int N       = n_items + n_usr;

    float* out_final = (float*)d_out;                        // (n_ent,64)
    float* out_u     = out_final + (size_t)n_ent * 64;       // (n_usr,64)
    float* out_items = out_u + (size_t)n_usr * 64;           // (n_items,64)

    float* ws = (float*)d_ws;
    size_t o = 0;
    // --- contiguous histogram block (single memset) ---
    int*   deg_e = (int*)(ws + o);  o += n_ent;
    int*   gt_e  = (int*)(ws + o);  o += 1;
    int*   deg_u = (int*)(ws + o);  o += n_usr;
    int*   gt_u  = (int*)(ws + o);  o += 1;
    int*   deg_i = (int*)(ws + o);  o += n_items;
    int*   gt_i  = (int*)(ws + o);  o += 1;
    size_t hist_len = ((size_t)(n_ent + n_usr + n_items) + 3) * sizeof(int);
    // --- bases/cursors (written by alloc, no zeroing) ---
    int*   base_e = (int*)(ws + o); o += n_ent;
    int*   cur_e  = (int*)(ws + o); o += n_ent;
    int*   base_u = (int*)(ws + o); o += n_usr;
    int*   cur_u  = (int*)(ws + o); o += n_usr;
    int*   base_i = (int*)(ws + o); o += n_items;
    int*   cur_i  = (int*)(ws + o); o += n_items;
    o = (o + 3) & ~(size_t)3;                      // 16B align
    float4* pay_kg = (float4*)(ws + o); o += (size_t)E_kg * 4;
    int*    pay_iu = (int*)(ws + o);    o += E_iu;
    o = (o + 1) & ~(size_t)1;                      // 8B align
    float2* pay_ui = (float2*)(ws + o); o += (size_t)E_ui * 2;
    float* normv = ws + o;          o += N;
    o = (o + 3) & ~(size_t)3;                      // 16B align for float4 reads
    float* icf   = ws + o;          o += (size_t)n_items * 64;

    hipMemsetAsync(deg_e, 0, hist_len, stream);

    // CSR builds (all three graphs, two launches)
    int tot_hist = E_kg + E_iu + E_ui;
    hist3_k<<<(tot_hist + 255) / 256, 256, 0, stream>>>(kg_src, iu_dst, ui_dst,
                                                        deg_e, deg_u, deg_i,
                                                        E_kg, E_iu, E_ui, n_items, N);
    int tot_alloc = n_ent + n_usr + n_items;
    alloc3_k<<<(tot_alloc + 255) / 256, 256, 0, stream>>>(deg_e, deg_u, deg_i,
                                                          base_e, cur_e, base_u, cur_u,
                                                          base_i, cur_i,
                                                          gt_e, gt_u, gt_i,
                                                          n_ent, n_usr, n_items);

    // KG compute
    kg_edge_fused_k<<<(E_kg + 63) / 64, 256, 0, stream>>>(ent, rel, kg_src, kg_dst,
                                                          kg_typ, cur_e, pay_kg, E_kg);
    kg_gather_k<<<(n_ent + 3) / 4, 256, 0, stream>>>(ent, rel, deg_e, base_e, pay_kg,
                                                     out_final, out_items, normv,
                                                     n_items, n_ent);
    user_norm_k<<<(n_usr + 3) / 4, 256, 0, stream>>>(usr, normv, n_items, n_usr);

    // CF scatters + gathers
    iu_scat_k<<<(E_iu + 255) / 256, 256, 0, stream>>>(iu_src, iu_dst, cur_u, pay_iu,
                                                      n_items, N, E_iu);
    ui_scat_k<<<(E_ui + 255) / 256, 256, 0, stream>>>(ui_src, ui_dst, normv, cur_i,
                                                      pay_ui, n_items, E_ui);
    iu_gather_k<<<(n_usr + 3) / 4, 256, 0, stream>>>(out_items, usr, deg_u, base_u,
                                                     pay_iu, out_u, n_items, n_usr);
    ui_gather_k<<<(n_items + 3) / 4, 256, 0, stream>>>(out_items, usr, normv, deg_i,
                                                       base_i, pay_ui, icf, n_items,
                                                       n_items);
    fusion_mfma_k<<<(n_items + 63) / 64, 256, 0, stream>>>(out_items, icf, W1, W2,
                                                           out_final, n_items);
}

// Round 9
// 384.076 us; speedup vs baseline: 2.1314x; 1.0040x over previous
//
#include <hip/hip_runtime.h>
#include <cstdint>

#define EPSF 1e-15f
#define MAXN (1.0f - 1e-5f)

typedef __attribute__((ext_vector_type(8))) short bf16x8;
typedef __attribute__((ext_vector_type(4))) float f32x4;

__device__ __forceinline__ float wsum64(float v) {
    v += __shfl_xor(v, 1);
    v += __shfl_xor(v, 2);
    v += __shfl_xor(v, 4);
    v += __shfl_xor(v, 8);
    v += __shfl_xor(v, 16);
    v += __shfl_xor(v, 32);
    return v;
}

__device__ __forceinline__ float dot4(float4 a, float4 b) {
    return a.x * b.x + a.y * b.y + a.z * b.z + a.w * b.w;
}

// fast reciprocal (v_rcp_f32, ~1e-7 rel err)
__device__ __forceinline__ float frcp(float x) {
    return __builtin_amdgcn_rcpf(x);
}

// fast tanh for x >= 0: (e^{2x}-1)/(e^{2x}+1); clamp avoids inf/inf
__device__ __forceinline__ float tanh_f(float x) {
    x = fminf(x, 10.f);
    float t = __expf(2.f * x);
    return (t - 1.f) * frcp(t + 1.f);
}

// fast atanh for 0 <= x <= MAXN
__device__ __forceinline__ float atanh_f(float x) {
    return 0.5f * __logf((1.f + x) * frcp(1.f - x));
}

__device__ __forceinline__ short f2bf(float f) {
    uint32_t b = __float_as_uint(f);
    b = (b + 0x7FFF + ((b >> 16) & 1)) >> 16;
    return (short)b;
}

__device__ __forceinline__ bf16x8 pack8(const float* __restrict__ p) {
    float4 lo = *(const float4*)p;
    float4 hi = *(const float4*)(p + 4);
    bf16x8 r;
    r[0] = f2bf(lo.x); r[1] = f2bf(lo.y); r[2] = f2bf(lo.z); r[3] = f2bf(lo.w);
    r[4] = f2bf(hi.x); r[5] = f2bf(hi.y); r[6] = f2bf(hi.z); r[7] = f2bf(hi.w);
    return r;
}

// combined histogram for all three graphs (one launch)
__global__ void hist3_k(const int* __restrict__ kg_src, const int* __restrict__ iu_dst,
                        const int* __restrict__ ui_dst,
                        int* __restrict__ deg_e, int* __restrict__ deg_u,
                        int* __restrict__ deg_i,
                        int E_kg, int E_iu, int E_ui, int n_items, int N) {
    int t = blockIdx.x * blockDim.x + threadIdx.x;
    if (t < E_kg) { atomicAdd(&deg_e[kg_src[t]], 1); return; }
    t -= E_kg;
    if (t < E_iu) {
        int d = iu_dst[t];
        if (d >= n_items && d < N) atomicAdd(&deg_u[d - n_items], 1);
        return;
    }
    t -= E_iu;
    if (t < E_ui) {
        int d = ui_dst[t];
        if (d < n_items) atomicAdd(&deg_i[d], 1);
    }
}

// combined CSR segment allocation for all three graphs (one launch)
__global__ void alloc3_k(const int* __restrict__ deg_e, const int* __restrict__ deg_u,
                         const int* __restrict__ deg_i,
                         int* __restrict__ base_e, int* __restrict__ cur_e,
                         int* __restrict__ base_u, int* __restrict__ cur_u,
                         int* __restrict__ base_i, int* __restrict__ cur_i,
                         int* __restrict__ gt_e, int* __restrict__ gt_u,
                         int* __restrict__ gt_i,
                         int n_ent, int n_usr, int n_items) {
    int t = blockIdx.x * blockDim.x + threadIdx.x;
    if (t < n_ent) { int b = atomicAdd(gt_e, deg_e[t]); base_e[t] = b; cur_e[t] = b; return; }
    t -= n_ent;
    if (t < n_usr) { int b = atomicAdd(gt_u, deg_u[t]); base_u[t] = b; cur_u[t] = b; return; }
    t -= n_usr;
    if (t < n_items) { int b = atomicAdd(gt_i, deg_i[t]); base_i[t] = b; cur_i[t] = b; }
}

// ---------------- KG path ----------------

// Merged dots+chain: 4 lanes/edge coalesced row reads, 2-step shfl reduce,
// fast-math scalar chain run 4x-redundant, lane 0 scatters CSR payload.
__global__ __launch_bounds__(256) void kg_edge_fused_k(const float* __restrict__ ent,
                          const float* __restrict__ rel,
                          const int* __restrict__ src,
                          const int* __restrict__ dst,
                          const int* __restrict__ typ,
                          int* __restrict__ cursor,
                          float4* __restrict__ payload,
                          int nE) {
    int w = blockIdx.x * 4 + (threadIdx.x >> 6);
    int l = threadIdx.x & 63;
    int e = w * 16 + (l >> 2);
    if (e >= nE) return;
    int j0 = l & 3;
    int s = src[e], d = dst[e], ty = typ[e] + 2;
    const float4* pu = (const float4*)(ent + (size_t)s * 64);
    const float4* pv = (const float4*)(ent + (size_t)d * 64);
    const float4* pr = (const float4*)(rel + (size_t)ty * 64);

    float uu = 0.f, vv = 0.f, rr = 0.f, uv = 0.f, ur = 0.f, vr = 0.f;
#pragma unroll
    for (int i = 0; i < 4; ++i) {
        float4 a = pu[4 * i + j0], b = pv[4 * i + j0], c = pr[4 * i + j0];
        uu += dot4(a, a); vv += dot4(b, b); rr += dot4(c, c);
        uv += dot4(a, b); ur += dot4(a, c); vr += dot4(b, c);
    }
#pragma unroll
    for (int m = 1; m < 4; m <<= 1) {
        uu += __shfl_xor(uu, m);
        vv += __shfl_xor(vv, m);
        rr += __shfl_xor(rr, m);
        uv += __shfl_xor(uv, m);
        ur += __shfl_xor(ur, m);
        vr += __shfl_xor(vr, m);
    }

    float n0 = sqrtf(fmaxf(uu, EPSF));
    float cp = tanh_f(n0) * frcp(n0);
    float p2 = cp * cp * uu;
    float om_p2 = 1.f - p2;
    float lam = 2.f * frcp(fmaxf(om_p2, EPSF));

    float nv = sqrtf(fmaxf(vv, EPSF));
    float cd = tanh_f(0.5f * lam * nv) * frcp(nv);
    float wd2 = cd * cd * vv;
    float pwd = cp * cd * uv;
    float iDd = frcp(fmaxf(1.f + 2.f * pwd + p2 * wd2, EPSF));
    float a1 = (1.f + 2.f * pwd + wd2) * cp * iDd;
    float b1 = om_p2 * cd * iDd;

    float nr = sqrtf(fmaxf(rr, EPSF));
    float cr = tanh_f(0.5f * lam * nr) * frcp(nr);
    float wr2 = cr * cr * rr;
    float pwr = cp * cr * ur;
    float iDr = frcp(fmaxf(1.f + 2.f * pwr + p2 * wr2, EPSF));
    float a2 = (1.f + 2.f * pwr + wr2) * cp * iDr;
    float c2 = om_p2 * cr * iDr;

    float x2 = a1 * a1 * uu + 2.f * a1 * b1 * uv + b1 * b1 * vv;
    float y2 = a2 * a2 * uu + 2.f * a2 * c2 * ur + c2 * c2 * rr;
    float xy = a1 * a2 * uu + a1 * c2 * ur + b1 * a2 * uv + b1 * c2 * vr;
    float iden = frcp(fmaxf(1.f + 2.f * xy + x2 * y2, EPSF));
    float E = (1.f + 2.f * xy + y2) * iden;
    float F = (1.f - x2) * iden;
    float zu = E * a1 + F * a2;
    float zv = E * b1;
    float zr = F * c2;

    float z2 = zu * zu * uu + zv * zv * vv + zr * zr * rr
             + 2.f * (zu * zv * uv + zu * zr * ur + zv * zr * vr);
    float nz = sqrtf(fmaxf(z2, EPSF));
    if (nz > MAXN) {
        float sc = MAXN * frcp(nz);
        zu *= sc; zv *= sc; zr *= sc;
        z2 *= sc * sc;
    }

    float mxy = -cp * (zu * uu + zv * uv + zr * ur);
    float idenl = frcp(fmaxf(1.f + 2.f * mxy + p2 * z2, EPSF));
    float G = (1.f + 2.f * mxy + z2) * idenl;
    float H = om_p2 * idenl;
    float su = -G * cp + H * zu;
    float sv = H * zv;
    float sr = H * zr;

    float ns2 = su * su * uu + sv * sv * vv + sr * sr * rr
              + 2.f * (su * sv * uv + su * sr * ur + sv * sr * vr);
    float ns = sqrtf(fmaxf(ns2, EPSF));
    float k = fmaxf(om_p2, EPSF) * atanh_f(fminf(ns, MAXN)) * frcp(ns);

    if (j0 == 0) {
        int pos = atomicAdd(&cursor[s], 1);
        payload[pos] = make_float4(k * sv, k * sr, k * su,
                                   __int_as_float(d | (ty << 18)));
    }
}

// Wave-per-entity CSR gather, 4x unrolled; also emits item-row norms.
__global__ void kg_gather_k(const float* __restrict__ ent,
                            const float* __restrict__ rel,
                            const int* __restrict__ deg,
                            const int* __restrict__ base,
                            const float4* __restrict__ payload,
                            float* __restrict__ out_final,
                            float* __restrict__ out_items,
                            float* __restrict__ normv,
                            int n_items, int n) {
    int i = blockIdx.x * (blockDim.x >> 6) + (threadIdx.x >> 6);
    if (i >= n) return;
    int l = threadIdx.x & 63;
    int b = base[i], dg = deg[i];
    float acc = 0.f, as = 0.f;
    int q = 0;
    for (; q + 4 <= dg; q += 4) {
        float4 p0 = payload[b + q];
        float4 p1 = payload[b + q + 1];
        float4 p2 = payload[b + q + 2];
        float4 p3 = payload[b + q + 3];
        int w0 = __float_as_int(p0.w), w1 = __float_as_int(p1.w);
        int w2 = __float_as_int(p2.w), w3 = __float_as_int(p3.w);
        float v0 = ent[(size_t)(w0 & 0x3FFFF) * 64 + l];
        float r0 = rel[(size_t)(w0 >> 18) * 64 + l];
        float v1 = ent[(size_t)(w1 & 0x3FFFF) * 64 + l];
        float r1 = rel[(size_t)(w1 >> 18) * 64 + l];
        float v2 = ent[(size_t)(w2 & 0x3FFFF) * 64 + l];
        float r2 = rel[(size_t)(w2 >> 18) * 64 + l];
        float v3 = ent[(size_t)(w3 & 0x3FFFF) * 64 + l];
        float r3 = rel[(size_t)(w3 >> 18) * 64 + l];
        acc += p0.x * v0 + p0.y * r0 + p1.x * v1 + p1.y * r1;
        acc += p2.x * v2 + p2.y * r2 + p3.x * v3 + p3.y * r3;
        as += (p0.z + p1.z) + (p2.z + p3.z);
    }
    for (; q < dg; ++q) {
        float4 p = payload[b + q];
        int w = __float_as_int(p.w);
        acc += p.x * ent[(size_t)(w & 0x3FFFF) * 64 + l]
             + p.y * rel[(size_t)(w >> 18) * 64 + l];
        as += p.z;
    }
    float v = (acc + as * ent[(size_t)i * 64 + l]) * frcp(fmaxf((float)dg, 1.f));
    if (i < n_items) {
        out_items[(size_t)i * 64 + l] = v;
        float s2 = wsum64(v * v);
        if (l == 0) normv[i] = s2;
    } else {
        out_final[(size_t)i * 64 + l] = v;
    }
}

// norms for the user half of cat_nodes
__global__ void user_norm_k(const float* __restrict__ user, float* __restrict__ normv,
                            int n_items, int n_usr) {
    int j = blockIdx.x * (blockDim.x >> 6) + (threadIdx.x >> 6);
    if (j >= n_usr) return;
    int l = threadIdx.x & 63;
    float c = user[(size_t)j * 64 + l];
    float s = wsum64(c * c);
    if (l == 0) normv[n_items + j] = s;
}

// ---------------- CF path ----------------

// iu scatter: payload = src index at CSR slot of (dst - n_items)
__global__ void iu_scat_k(const int* __restrict__ srcA, const int* __restrict__ dstA,
                          int* __restrict__ cursor, int* __restrict__ payload,
                          int n_items, int N, int nE) {
    int e = blockIdx.x * blockDim.x + threadIdx.x;
    if (e >= nE) return;
    int d = dstA[e];
    if (d < n_items || d >= N) return;
    int pos = atomicAdd(&cursor[d - n_items], 1);
    payload[pos] = srcA[e];
}

// ui scatter: payload = {src, 1/(norm[src]+1e-6)} at CSR slot of dst
__global__ void ui_scat_k(const int* __restrict__ srcA, const int* __restrict__ dstA,
                          const float* __restrict__ normv,
                          int* __restrict__ cursor, float2* __restrict__ payload,
                          int n_items, int nE) {
    int e = blockIdx.x * blockDim.x + threadIdx.x;
    if (e >= nE) return;
    int d = dstA[e];
    if (d >= n_items) return;
    int s = srcA[e];
    int pos = atomicAdd(&cursor[d], 1);
    payload[pos] = make_float2(__int_as_float(s), frcp(normv[s] + 1e-6f));
}

// wave-per-user gather, 8x unrolled: out_u = (sum cat[src]) / deg
__global__ void iu_gather_k(const float* __restrict__ items, const float* __restrict__ user,
                            const int* __restrict__ deg, const int* __restrict__ base,
                            const int* __restrict__ payload,
                            float* __restrict__ out_u, int n_items, int n) {
    int i = blockIdx.x * (blockDim.x >> 6) + (threadIdx.x >> 6);
    if (i >= n) return;
    int l = threadIdx.x & 63;
    int b = base[i], dg = deg[i];
    float acc = 0.f;
    int q = 0;
    for (; q + 8 <= dg; q += 8) {
        float vs[8];
#pragma unroll
        for (int j = 0; j < 8; ++j) {
            int s0 = payload[b + q + j];
            vs[j] = (s0 < n_items) ? items[(size_t)s0 * 64 + l]
                                   : user[(size_t)(s0 - n_items) * 64 + l];
        }
#pragma unroll
        for (int j = 0; j < 8; ++j) acc += vs[j];
    }
    for (; q < dg; ++q) {
        int s0 = payload[b + q];
        acc += (s0 < n_items) ? items[(size_t)s0 * 64 + l]
                              : user[(size_t)(s0 - n_items) * 64 + l];
    }
    out_u[(size_t)i * 64 + l] = acc * frcp(fmaxf((float)dg, 1.f));
}

// wave-per-item gather, 8x unrolled: icf = norm[i]*(sum f_e*cat[src_e])/deg
__global__ void ui_gather_k(const float* __restrict__ items, const float* __restrict__ user,
                            const float* __restrict__ normv,
                            const int* __restrict__ deg, const int* __restrict__ base,
                            const float2* __restrict__ payload,
                            float* __restrict__ icf, int n_items, int n) {
    int i = blockIdx.x * (blockDim.x >> 6) + (threadIdx.x >> 6);
    if (i >= n) return;
    int l = threadIdx.x & 63;
    int b = base[i], dg = deg[i];
    float acc = 0.f;
    int q = 0;
    for (; q + 8 <= dg; q += 8) {
        float2 ps[8];
        float vs[8];
#pragma unroll
        for (int j = 0; j < 8; ++j) ps[j] = payload[b + q + j];
#pragma unroll
        for (int j = 0; j < 8; ++j) {
            int s0 = __float_as_int(ps[j].x);
            vs[j] = (s0 < n_items) ? items[(size_t)s0 * 64 + l]
                                   : user[(size_t)(s0 - n_items) * 64 + l];
        }
#pragma unroll
        for (int j = 0; j < 8; ++j) acc += ps[j].y * vs[j];
    }
    for (; q < dg; ++q) {
        float2 p0 = payload[b + q];
        int s0 = __float_as_int(p0.x);
        acc += p0.y * ((s0 < n_items) ? items[(size_t)s0 * 64 + l]
                                      : user[(size_t)(s0 - n_items) * 64 + l]);
    }
    icf[(size_t)i * 64 + l] = normv[i] * acc * frcp(fmaxf((float)dg, 1.f));
}

// MFMA gate+fusion: acc = [oi|cf] @ [W1;W2]^T (bf16), out = g*oi + (1-g)*cf.
__global__ __launch_bounds__(256) void fusion_mfma_k(const float* __restrict__ items,
                          const float* __restrict__ icf,
                          const float* __restrict__ W1, const float* __restrict__ W2,
                          float* __restrict__ outf, int n_items) {
    int lane = threadIdx.x & 63;
    int row0 = blockIdx.x * 64 + (threadIdx.x >> 6) * 16;
    int r = lane & 15, g = lane >> 4;

    int arow = row0 + r;
    size_t rbase = (size_t)(arow < n_items ? arow : 0) * 64;

    bf16x8 afrag[4];
#pragma unroll
    for (int s = 0; s < 4; ++s) {
        int kb = s * 32 + g * 8;
        const float* p = (kb < 64) ? (items + rbase + kb) : (icf + rbase + kb - 64);
        afrag[s] = pack8(p);
    }

    bf16x8 bfrag[4][4];
#pragma unroll
    for (int c = 0; c < 4; ++c) {
        int col = c * 16 + r;
#pragma unroll
        for (int s = 0; s < 4; ++s) {
            int kb = s * 32 + g * 8;
            const float* p = (kb < 64) ? (W1 + col * 64 + kb) : (W2 + col * 64 + kb - 64);
            bfrag[c][s] = pack8(p);
        }
    }

    f32x4 acc[4] = {{0.f,0.f,0.f,0.f},{0.f,0.f,0.f,0.f},
                    {0.f,0.f,0.f,0.f},{0.f,0.f,0.f,0.f}};
#pragma unroll
    for (int s = 0; s < 4; ++s)
#pragma unroll
        for (int c = 0; c < 4; ++c)
            acc[c] = __builtin_amdgcn_mfma_f32_16x16x32_bf16(afrag[s], bfrag[c][s],
                                                             acc[c], 0, 0, 0);

#pragma unroll
    for (int c = 0; c < 4; ++c) {
        int col = c * 16 + r;
#pragma unroll
        for (int q = 0; q < 4; ++q) {
            int orow = row0 + g * 4 + q;
            if (orow < n_items) {
                size_t off = (size_t)orow * 64 + col;
                float oi = items[off], cf = icf[off];
                float gate = frcp(1.f + __expf(-acc[c][q]));
                outf[off] = gate * oi + (1.f - gate) * cf;
            }
        }
    }
}

extern "C" void kernel_launch(void* const* d_in, const int* in_sizes, int n_in,
                              void* d_out, int out_size, void* d_ws, size_t ws_size,
                              hipStream_t stream) {
    const float* ent    = (const float*)d_in[0];
    const float* usr    = (const float*)d_in[1];
    const float* rel    = (const float*)d_in[2];
    const float* W1     = (const float*)d_in[3];
    const float* W2     = (const float*)d_in[4];
    const int*   kg_src = (const int*)d_in[5];
    const int*   kg_dst = (const int*)d_in[6];
    const int*   kg_typ = (const int*)d_in[7];
    const int*   iu_src = (const int*)d_in[8];
    const int*   iu_dst = (const int*)d_in[9];
    const int*   ui_src = (const int*)d_in[10];
    const int*   ui_dst = (const int*)d_in[11];

    const int n_ent   = in_sizes[0] / 64;
    const int n_usr   = in_sizes[1] / 64;
    const int E_kg    = in_sizes[5];
    const int E_iu    = in_sizes[8];
    const int E_ui    = in_sizes[10];
    const int n_items = (out_size - in_sizes[0] - in_sizes[1]) / 64;
    const int N       = n_items + n_usr;

    float* out_final = (float*)d_out;                        // (n_ent,64)
    float* out_u     = out_final + (size_t)n_ent * 64;       // (n_usr,64)
    float* out_items = out_u + (size_t)n_usr * 64;           // (n_items,64)

    float* ws = (float*)d_ws;
    size_t o = 0;
    // --- contiguous histogram block (single memset) ---
    int*   deg_e = (int*)(ws + o);  o += n_ent;
    int*   gt_e  = (int*)(ws + o);  o += 1;
    int*   deg_u = (int*)(ws + o);  o += n_usr;
    int*   gt_u  = (int*)(ws + o);  o += 1;
    int*   deg_i = (int*)(ws + o);  o += n_items;
    int*   gt_i  = (int*)(ws + o);  o += 1;
    size_t hist_len = ((size_t)(n_ent + n_usr + n_items) + 3) * sizeof(int);
    // --- bases/cursors (written by alloc, no zeroing) ---
    int*   base_e = (int*)(ws + o); o += n_ent;
    int*   cur_e  = (int*)(ws + o); o += n_ent;
    int*   base_u = (int*)(ws + o); o += n_usr;
    int*   cur_u  = (int*)(ws + o); o += n_usr;
    int*   base_i = (int*)(ws + o); o += n_items;
    int*   cur_i  = (int*)(ws + o); o += n_items;
    o = (o + 3) & ~(size_t)3;                      // 16B align
    float4* pay_kg = (float4*)(ws + o); o += (size_t)E_kg * 4;
    int*    pay_iu = (int*)(ws + o);    o += E_iu;
    o = (o + 1) & ~(size_t)1;                      // 8B align
    float2* pay_ui = (float2*)(ws + o); o += (size_t)E_ui * 2;
    float* normv = ws + o;          o += N;
    o = (o + 3) & ~(size_t)3;                      // 16B align for float4 reads
    float* icf   = ws + o;          o += (size_t)n_items * 64;

    hipMemsetAsync(deg_e, 0, hist_len, stream);

    // CSR builds (all three graphs, two launches)
    int tot_hist = E_kg + E_iu + E_ui;
    hist3_k<<<(tot_hist + 255) / 256, 256, 0, stream>>>(kg_src, iu_dst, ui_dst,
                                                        deg_e, deg_u, deg_i,
                                                        E_kg, E_iu, E_ui, n_items, N);
    int tot_alloc = n_ent + n_usr + n_items;
    alloc3_k<<<(tot_alloc + 255) / 256, 256, 0, stream>>>(deg_e, deg_u, deg_i,
                                                          base_e, cur_e, base_u, cur_u,
                                                          base_i, cur_i,
                                                          gt_e, gt_u, gt_i,
                                                          n_ent, n_usr, n_items);

    // KG compute
    kg_edge_fused_k<<<(E_kg + 63) / 64, 256, 0, stream>>>(ent, rel, kg_src, kg_dst,
                                                          kg_typ, cur_e, pay_kg, E_kg);
    kg_gather_k<<<(n_ent + 3) / 4, 256, 0, stream>>>(ent, rel, deg_e, base_e, pay_kg,
                                                     out_final, out_items, normv,
                                                     n_items, n_ent);
    user_norm_k<<<(n_usr + 3) / 4, 256, 0, stream>>>(usr, normv, n_items, n_usr);

    // CF scatters + gathers
    iu_scat_k<<<(E_iu + 255) / 256, 256, 0, stream>>>(iu_src, iu_dst, cur_u, pay_iu,
                                                      n_items, N, E_iu);
    ui_scat_k<<<(E_ui + 255) / 256, 256, 0, stream>>>(ui_src, ui_dst, normv, cur_i,
                                                      pay_ui, n_items, E_ui);
    iu_gather_k<<<(n_usr + 3) / 4, 256, 0, stream>>>(out_items, usr, deg_u, base_u,
                                                     pay_iu, out_u, n_items, n_usr);
    ui_gather_k<<<(n_items + 3) / 4, 256, 0, stream>>>(out_items, usr, normv, deg_i,
                                                       base_i, pay_ui, icf, n_items,
                                                       n_items);
    fusion_mfma_k<<<(n_items + 63) / 64, 256, 0, stream>>>(out_items, icf, W1, W2,
                                                           out_final, n_items);
}

// Round 10
// 322.313 us; speedup vs baseline: 2.5399x; 1.1916x over previous
//
#include <hip/hip_runtime.h>
#include <cstdint>

#define EPSF 1e-15f
#define MAXN (1.0f - 1e-5f)

typedef __attribute__((ext_vector_type(8))) short bf16x8;
typedef __attribute__((ext_vector_type(4))) float f32x4;

__device__ __forceinline__ float wsum64(float v) {
    v += __shfl_xor(v, 1);
    v += __shfl_xor(v, 2);
    v += __shfl_xor(v, 4);
    v += __shfl_xor(v, 8);
    v += __shfl_xor(v, 16);
    v += __shfl_xor(v, 32);
    return v;
}

__device__ __forceinline__ float dot4(float4 a, float4 b) {
    return a.x * b.x + a.y * b.y + a.z * b.z + a.w * b.w;
}

__device__ __forceinline__ float frcp(float x) {
    return __builtin_amdgcn_rcpf(x);
}

__device__ __forceinline__ float tanh_f(float x) {
    x = fminf(x, 10.f);
    float t = __expf(2.f * x);
    return (t - 1.f) * frcp(t + 1.f);
}

__device__ __forceinline__ float atanh_f(float x) {
    return 0.5f * __logf((1.f + x) * frcp(1.f - x));
}

__device__ __forceinline__ short f2bf(float f) {
    uint32_t b = __float_as_uint(f);
    b = (b + 0x7FFF + ((b >> 16) & 1)) >> 16;
    return (short)b;
}

__device__ __forceinline__ bf16x8 pack8(const float* __restrict__ p) {
    float4 lo = *(const float4*)p;
    float4 hi = *(const float4*)(p + 4);
    bf16x8 r;
    r[0] = f2bf(lo.x); r[1] = f2bf(lo.y); r[2] = f2bf(lo.z); r[3] = f2bf(lo.w);
    r[4] = f2bf(hi.x); r[5] = f2bf(hi.y); r[6] = f2bf(hi.z); r[7] = f2bf(hi.w);
    return r;
}

// Combined hist+rank for all three graphs: rank[e] = old count (the CSR rank).
// 8 edges/thread -> 8 independent atomics in flight (attacks atomic latency).
__global__ __launch_bounds__(256) void rank3_k(
        const int* __restrict__ kg_src, const int* __restrict__ iu_dst,
        const int* __restrict__ ui_dst,
        int* __restrict__ deg_e, int* __restrict__ deg_u, int* __restrict__ deg_i,
        int* __restrict__ rank_kg, int* __restrict__ rank_iu, int* __restrict__ rank_ui,
        int E_kg, int E_iu, int E_ui, int n_items, int N) {
    long b0 = (long)blockIdx.x * 2048 + threadIdx.x;
#pragma unroll
    for (int j = 0; j < 8; ++j) {
        long t = b0 + j * 256;
        if (t < E_kg) {
            rank_kg[t] = atomicAdd(&deg_e[kg_src[t]], 1);
            continue;
        }
        t -= E_kg;
        if (t < E_iu) {
            int d = iu_dst[t];
            if (d >= n_items && d < N) rank_iu[t] = atomicAdd(&deg_u[d - n_items], 1);
            continue;
        }
        t -= E_iu;
        if (t < E_ui) {
            int d = ui_dst[t];
            if (d < n_items) rank_ui[t] = atomicAdd(&deg_i[d], 1);
        }
    }
}

// CSR base allocation via block scan + 1 atomic per block (order-free bases).
// Grid = Be + Bu + Bi blocks; each block owns 256 nodes of one segment.
__global__ __launch_bounds__(256) void alloc3_k(
        const int* __restrict__ deg_e, const int* __restrict__ deg_u,
        const int* __restrict__ deg_i,
        int* __restrict__ base_e, int* __restrict__ base_u, int* __restrict__ base_i,
        int* __restrict__ gt_e, int* __restrict__ gt_u, int* __restrict__ gt_i,
        int n_ent, int n_usr, int n_items, int Be, int Bu) {
    const int* deg; int* base; int* gt; int n; int boff;
    int b = blockIdx.x;
    if (b < Be)           { deg = deg_e; base = base_e; gt = gt_e; n = n_ent;   boff = b; }
    else if (b < Be + Bu) { deg = deg_u; base = base_u; gt = gt_u; n = n_usr;   boff = b - Be; }
    else                  { deg = deg_i; base = base_i; gt = gt_i; n = n_items; boff = b - Be - Bu; }

    int t = boff * 256 + threadIdx.x;
    int v = (t < n) ? deg[t] : 0;
    int lane = threadIdx.x & 63, w = threadIdx.x >> 6;

    int inc = v;
#pragma unroll
    for (int off = 1; off < 64; off <<= 1) {
        int u = __shfl_up(inc, off);
        if (lane >= off) inc += u;
    }

    __shared__ int wtot[4];
    __shared__ int bbase;
    if (lane == 63) wtot[w] = inc;
    __syncthreads();
    if (threadIdx.x == 0) {
        int s = 0;
#pragma unroll
        for (int i = 0; i < 4; ++i) { int x = wtot[i]; wtot[i] = s; s += x; }
        bbase = atomicAdd(gt, s);
    }
    __syncthreads();
    if (t < n) base[t] = bbase + wtot[w] + inc - v;
}

// ---------------- KG path ----------------

// Merged dots+chain: 4 lanes/edge coalesced reads, 2-step shfl reduce,
// fast-math chain 4x-redundant; payload slot = base[s] + rank[e] (no atomic).
__global__ __launch_bounds__(256) void kg_edge_fused_k(const float* __restrict__ ent,
                          const float* __restrict__ rel,
                          const int* __restrict__ src,
                          const int* __restrict__ dst,
                          const int* __restrict__ typ,
                          const int* __restrict__ base,
                          const int* __restrict__ rankv,
                          float4* __restrict__ payload,
                          int nE) {
    int w = blockIdx.x * 4 + (threadIdx.x >> 6);
    int l = threadIdx.x & 63;
    int e = w * 16 + (l >> 2);
    if (e >= nE) return;
    int j0 = l & 3;
    int s = src[e], d = dst[e], ty = typ[e] + 2;
    const float4* pu = (const float4*)(ent + (size_t)s * 64);
    const float4* pv = (const float4*)(ent + (size_t)d * 64);
    const float4* pr = (const float4*)(rel + (size_t)ty * 64);

    float uu = 0.f, vv = 0.f, rr = 0.f, uv = 0.f, ur = 0.f, vr = 0.f;
#pragma unroll
    for (int i = 0; i < 4; ++i) {
        float4 a = pu[4 * i + j0], b = pv[4 * i + j0], c = pr[4 * i + j0];
        uu += dot4(a, a); vv += dot4(b, b); rr += dot4(c, c);
        uv += dot4(a, b); ur += dot4(a, c); vr += dot4(b, c);
    }
#pragma unroll
    for (int m = 1; m < 4; m <<= 1) {
        uu += __shfl_xor(uu, m);
        vv += __shfl_xor(vv, m);
        rr += __shfl_xor(rr, m);
        uv += __shfl_xor(uv, m);
        ur += __shfl_xor(ur, m);
        vr += __shfl_xor(vr, m);
    }

    float n0 = sqrtf(fmaxf(uu, EPSF));
    float cp = tanh_f(n0) * frcp(n0);
    float p2 = cp * cp * uu;
    float om_p2 = 1.f - p2;
    float lam = 2.f * frcp(fmaxf(om_p2, EPSF));

    float nv = sqrtf(fmaxf(vv, EPSF));
    float cd = tanh_f(0.5f * lam * nv) * frcp(nv);
    float wd2 = cd * cd * vv;
    float pwd = cp * cd * uv;
    float iDd = frcp(fmaxf(1.f + 2.f * pwd + p2 * wd2, EPSF));
    float a1 = (1.f + 2.f * pwd + wd2) * cp * iDd;
    float b1 = om_p2 * cd * iDd;

    float nr = sqrtf(fmaxf(rr, EPSF));
    float cr = tanh_f(0.5f * lam * nr) * frcp(nr);
    float wr2 = cr * cr * rr;
    float pwr = cp * cr * ur;
    float iDr = frcp(fmaxf(1.f + 2.f * pwr + p2 * wr2, EPSF));
    float a2 = (1.f + 2.f * pwr + wr2) * cp * iDr;
    float c2 = om_p2 * cr * iDr;

    float x2 = a1 * a1 * uu + 2.f * a1 * b1 * uv + b1 * b1 * vv;
    float y2 = a2 * a2 * uu + 2.f * a2 * c2 * ur + c2 * c2 * rr;
    float xy = a1 * a2 * uu + a1 * c2 * ur + b1 * a2 * uv + b1 * c2 * vr;
    float iden = frcp(fmaxf(1.f + 2.f * xy + x2 * y2, EPSF));
    float E = (1.f + 2.f * xy + y2) * iden;
    float F = (1.f - x2) * iden;
    float zu = E * a1 + F * a2;
    float zv = E * b1;
    float zr = F * c2;

    float z2 = zu * zu * uu + zv * zv * vv + zr * zr * rr
             + 2.f * (zu * zv * uv + zu * zr * ur + zv * zr * vr);
    float nz = sqrtf(fmaxf(z2, EPSF));
    if (nz > MAXN) {
        float sc = MAXN * frcp(nz);
        zu *= sc; zv *= sc; zr *= sc;
        z2 *= sc * sc;
    }

    float mxy = -cp * (zu * uu + zv * uv + zr * ur);
    float idenl = frcp(fmaxf(1.f + 2.f * mxy + p2 * z2, EPSF));
    float G = (1.f + 2.f * mxy + z2) * idenl;
    float H = om_p2 * idenl;
    float su = -G * cp + H * zu;
    float sv = H * zv;
    float sr = H * zr;

    float ns2 = su * su * uu + sv * sv * vv + sr * sr * rr
              + 2.f * (su * sv * uv + su * sr * ur + sv * sr * vr);
    float ns = sqrtf(fmaxf(ns2, EPSF));
    float k = fmaxf(om_p2, EPSF) * atanh_f(fminf(ns, MAXN)) * frcp(ns);

    if (j0 == 0) {
        int pos = base[s] + rankv[e];
        payload[pos] = make_float4(k * sv, k * sr, k * su,
                                   __int_as_float(d | (ty << 18)));
    }
}

// Wave-per-entity CSR gather, 4x unrolled; also emits item-row norms.
__global__ void kg_gather_k(const float* __restrict__ ent,
                            const float* __restrict__ rel,
                            const int* __restrict__ deg,
                            const int* __restrict__ base,
                            const float4* __restrict__ payload,
                            float* __restrict__ out_final,
                            float* __restrict__ out_items,
                            float* __restrict__ normv,
                            int n_items, int n) {
    int i = blockIdx.x * (blockDim.x >> 6) + (threadIdx.x >> 6);
    if (i >= n) return;
    int l = threadIdx.x & 63;
    int b = base[i], dg = deg[i];
    float acc = 0.f, as = 0.f;
    int q = 0;
    for (; q + 4 <= dg; q += 4) {
        float4 p0 = payload[b + q];
        float4 p1 = payload[b + q + 1];
        float4 p2 = payload[b + q + 2];
        float4 p3 = payload[b + q + 3];
        int w0 = __float_as_int(p0.w), w1 = __float_as_int(p1.w);
        int w2 = __float_as_int(p2.w), w3 = __float_as_int(p3.w);
        float v0 = ent[(size_t)(w0 & 0x3FFFF) * 64 + l];
        float r0 = rel[(size_t)(w0 >> 18) * 64 + l];
        float v1 = ent[(size_t)(w1 & 0x3FFFF) * 64 + l];
        float r1 = rel[(size_t)(w1 >> 18) * 64 + l];
        float v2 = ent[(size_t)(w2 & 0x3FFFF) * 64 + l];
        float r2 = rel[(size_t)(w2 >> 18) * 64 + l];
        float v3 = ent[(size_t)(w3 & 0x3FFFF) * 64 + l];
        float r3 = rel[(size_t)(w3 >> 18) * 64 + l];
        acc += p0.x * v0 + p0.y * r0 + p1.x * v1 + p1.y * r1;
        acc += p2.x * v2 + p2.y * r2 + p3.x * v3 + p3.y * r3;
        as += (p0.z + p1.z) + (p2.z + p3.z);
    }
    for (; q < dg; ++q) {
        float4 p = payload[b + q];
        int w = __float_as_int(p.w);
        acc += p.x * ent[(size_t)(w & 0x3FFFF) * 64 + l]
             + p.y * rel[(size_t)(w >> 18) * 64 + l];
        as += p.z;
    }
    float v = (acc + as * ent[(size_t)i * 64 + l]) * frcp(fmaxf((float)dg, 1.f));
    if (i < n_items) {
        out_items[(size_t)i * 64 + l] = v;
        float s2 = wsum64(v * v);
        if (l == 0) normv[i] = s2;
    } else {
        out_final[(size_t)i * 64 + l] = v;
    }
}

// norms for the user half of cat_nodes
__global__ void user_norm_k(const float* __restrict__ user, float* __restrict__ normv,
                            int n_items, int n_usr) {
    int j = blockIdx.x * (blockDim.x >> 6) + (threadIdx.x >> 6);
    if (j >= n_usr) return;
    int l = threadIdx.x & 63;
    float c = user[(size_t)j * 64 + l];
    float s = wsum64(c * c);
    if (l == 0) normv[n_items + j] = s;
}

// ---------------- CF path ----------------

// iu scatter (no atomics): slot = base_u[d-n_items] + rank_iu[e]
__global__ void iu_scat_k(const int* __restrict__ srcA, const int* __restrict__ dstA,
                          const int* __restrict__ base, const int* __restrict__ rankv,
                          int* __restrict__ payload,
                          int n_items, int N, int nE) {
    int e = blockIdx.x * blockDim.x + threadIdx.x;
    if (e >= nE) return;
    int d = dstA[e];
    if (d < n_items || d >= N) return;
    payload[base[d - n_items] + rankv[e]] = srcA[e];
}

// ui scatter (no atomics): payload = {src, 1/(norm[src]+1e-6)}
__global__ void ui_scat_k(const int* __restrict__ srcA, const int* __restrict__ dstA,
                          const float* __restrict__ normv,
                          const int* __restrict__ base, const int* __restrict__ rankv,
                          float2* __restrict__ payload,
                          int n_items, int nE) {
    int e = blockIdx.x * blockDim.x + threadIdx.x;
    if (e >= nE) return;
    int d = dstA[e];
    if (d >= n_items) return;
    int s = srcA[e];
    payload[base[d] + rankv[e]] = make_float2(__int_as_float(s), frcp(normv[s] + 1e-6f));
}

// wave-per-user gather, 8x unrolled: out_u = (sum cat[src]) / deg
__global__ void iu_gather_k(const float* __restrict__ items, const float* __restrict__ user,
                            const int* __restrict__ deg, const int* __restrict__ base,
                            const int* __restrict__ payload,
                            float* __restrict__ out_u, int n_items, int n) {
    int i = blockIdx.x * (blockDim.x >> 6) + (threadIdx.x >> 6);
    if (i >= n) return;
    int l = threadIdx.x & 63;
    int b = base[i], dg = deg[i];
    float acc = 0.f;
    int q = 0;
    for (; q + 8 <= dg; q += 8) {
        float vs[8];
#pragma unroll
        for (int j = 0; j < 8; ++j) {
            int s0 = payload[b + q + j];
            vs[j] = (s0 < n_items) ? items[(size_t)s0 * 64 + l]
                                   : user[(size_t)(s0 - n_items) * 64 + l];
        }
#pragma unroll
        for (int j = 0; j < 8; ++j) acc += vs[j];
    }
    for (; q < dg; ++q) {
        int s0 = payload[b + q];
        acc += (s0 < n_items) ? items[(size_t)s0 * 64 + l]
                              : user[(size_t)(s0 - n_items) * 64 + l];
    }
    out_u[(size_t)i * 64 + l] = acc * frcp(fmaxf((float)dg, 1.f));
}

// wave-per-item gather, 8x unrolled: icf = norm[i]*(sum f_e*cat[src_e])/deg
__global__ void ui_gather_k(const float* __restrict__ items, const float* __restrict__ user,
                            const float* __restrict__ normv,
                            const int* __restrict__ deg, const int* __restrict__ base,
                            const float2* __restrict__ payload,
                            float* __restrict__ icf, int n_items, int n) {
    int i = blockIdx.x * (blockDim.x >> 6) + (threadIdx.x >> 6);
    if (i >= n) return;
    int l = threadIdx.x & 63;
    int b = base[i], dg = deg[i];
    float acc = 0.f;
    int q = 0;
    for (; q + 8 <= dg; q += 8) {
        float2 ps[8];
        float vs[8];
#pragma unroll
        for (int j = 0; j < 8; ++j) ps[j] = payload[b + q + j];
#pragma unroll
        for (int j = 0; j < 8; ++j) {
            int s0 = __float_as_int(ps[j].x);
            vs[j] = (s0 < n_items) ? items[(size_t)s0 * 64 + l]
                                   : user[(size_t)(s0 - n_items) * 64 + l];
        }
#pragma unroll
        for (int j = 0; j < 8; ++j) acc += ps[j].y * vs[j];
    }
    for (; q < dg; ++q) {
        float2 p0 = payload[b + q];
        int s0 = __float_as_int(p0.x);
        acc += p0.y * ((s0 < n_items) ? items[(size_t)s0 * 64 + l]
                                      : user[(size_t)(s0 - n_items) * 64 + l]);
    }
    icf[(size_t)i * 64 + l] = normv[i] * acc * frcp(fmaxf((float)dg, 1.f));
}

// MFMA gate+fusion: acc = [oi|cf] @ [W1;W2]^T (bf16), out = g*oi + (1-g)*cf.
__global__ __launch_bounds__(256) void fusion_mfma_k(const float* __restrict__ items,
                          const float* __restrict__ icf,
                          const float* __restrict__ W1, const float* __restrict__ W2,
                          float* __restrict__ outf, int n_items) {
    int lane = threadIdx.x & 63;
    int row0 = blockIdx.x * 64 + (threadIdx.x >> 6) * 16;
    int r = lane & 15, g = lane >> 4;

    int arow = row0 + r;
    size_t rbase = (size_t)(arow < n_items ? arow : 0) * 64;

    bf16x8 afrag[4];
#pragma unroll
    for (int s = 0; s < 4; ++s) {
        int kb = s * 32 + g * 8;
        const float* p = (kb < 64) ? (items + rbase + kb) : (icf + rbase + kb - 64);
        afrag[s] = pack8(p);
    }

    bf16x8 bfrag[4][4];
#pragma unroll
    for (int c = 0; c < 4; ++c) {
        int col = c * 16 + r;
#pragma unroll
        for (int s = 0; s < 4; ++s) {
            int kb = s * 32 + g * 8;
            const float* p = (kb < 64) ? (W1 + col * 64 + kb) : (W2 + col * 64 + kb - 64);
            bfrag[c][s] = pack8(p);
        }
    }

    f32x4 acc[4] = {{0.f,0.f,0.f,0.f},{0.f,0.f,0.f,0.f},
                    {0.f,0.f,0.f,0.f},{0.f,0.f,0.f,0.f}};
#pragma unroll
    for (int s = 0; s < 4; ++s)
#pragma unroll
        for (int c = 0; c < 4; ++c)
            acc[c] = __builtin_amdgcn_mfma_f32_16x16x32_bf16(afrag[s], bfrag[c][s],
                                                             acc[c], 0, 0, 0);

#pragma unroll
    for (int c = 0; c < 4; ++c) {
        int col = c * 16 + r;
#pragma unroll
        for (int q = 0; q < 4; ++q) {
            int orow = row0 + g * 4 + q;
            if (orow < n_items) {
                size_t off = (size_t)orow * 64 + col;
                float oi = items[off], cf = icf[off];
                float gate = frcp(1.f + __expf(-acc[c][q]));
                outf[off] = gate * oi + (1.f - gate) * cf;
            }
        }
    }
}

extern "C" void kernel_launch(void* const* d_in, const int* in_sizes, int n_in,
                              void* d_out, int out_size, void* d_ws, size_t ws_size,
                              hipStream_t stream) {
    const float* ent    = (const float*)d_in[0];
    const float* usr    = (const float*)d_in[1];
    const float* rel    = (const float*)d_in[2];
    const float* W1     = (const float*)d_in[3];
    const float* W2     = (const float*)d_in[4];
    const int*   kg_src = (const int*)d_in[5];
    const int*   kg_dst = (const int*)d_in[6];
    const int*   kg_typ = (const int*)d_in[7];
    const int*   iu_src = (const int*)d_in[8];
    const int*   iu_dst = (const int*)d_in[9];
    const int*   ui_src = (const int*)d_in[10];
    const int*   ui_dst = (const int*)d_in[11];

    const int n_ent   = in_sizes[0] / 64;
    const int n_usr   = in_sizes[1] / 64;
    const int E_kg    = in_sizes[5];
    const int E_iu    = in_sizes[8];
    const int E_ui    = in_sizes[10];
    const int n_items = (out_size - in_sizes[0] - in_sizes[1]) / 64;
    const int N       = n_items + n_usr;

    float* out_final = (float*)d_out;                        // (n_ent,64)
    float* out_u     = out_final + (size_t)n_ent * 64;       // (n_usr,64)
    float* out_items = out_u + (size_t)n_usr * 64;           // (n_items,64)

    // rank arrays live in the out_u chunk (12.8MB >= 8MB), consumed by
    // kg_edge/iu_scat/ui_scat, all BEFORE iu_gather_k writes out_u.
    int* rank_kg = (int*)out_u;
    int* rank_iu = rank_kg + E_kg;
    int* rank_ui = rank_iu + E_iu;

    float* ws = (float*)d_ws;
    size_t o = 0;
    // --- contiguous histogram block (single memset) ---
    int*   deg_e = (int*)(ws + o);  o += n_ent;
    int*   gt_e  = (int*)(ws + o);  o += 1;
    int*   deg_u = (int*)(ws + o);  o += n_usr;
    int*   gt_u  = (int*)(ws + o);  o += 1;
    int*   deg_i = (int*)(ws + o);  o += n_items;
    int*   gt_i  = (int*)(ws + o);  o += 1;
    size_t hist_len = ((size_t)(n_ent + n_usr + n_items) + 3) * sizeof(int);
    // --- bases (written by alloc, no zeroing; cursors eliminated) ---
    int*   base_e = (int*)(ws + o); o += n_ent;
    int*   base_u = (int*)(ws + o); o += n_usr;
    int*   base_i = (int*)(ws + o); o += n_items;
    o = (o + 3) & ~(size_t)3;                      // 16B align
    float4* pay_kg = (float4*)(ws + o); o += (size_t)E_kg * 4;
    int*    pay_iu = (int*)(ws + o);    o += E_iu;
    o = (o + 1) & ~(size_t)1;                      // 8B align
    float2* pay_ui = (float2*)(ws + o); o += (size_t)E_ui * 2;
    float* normv = ws + o;          o += N;
    o = (o + 3) & ~(size_t)3;                      // 16B align
    float* icf   = ws + o;          o += (size_t)n_items * 64;

    hipMemsetAsync(deg_e, 0, hist_len, stream);

    // hist+rank (one pass, 8 edges/thread), then scan-based base allocation
    long tot_hist = (long)E_kg + E_iu + E_ui;
    rank3_k<<<(int)((tot_hist + 2047) / 2048), 256, 0, stream>>>(
        kg_src, iu_dst, ui_dst, deg_e, deg_u, deg_i,
        rank_kg, rank_iu, rank_ui, E_kg, E_iu, E_ui, n_items, N);
    int Be = (n_ent + 255) / 256, Bu = (n_usr + 255) / 256, Bi = (n_items + 255) / 256;
    alloc3_k<<<Be + Bu + Bi, 256, 0, stream>>>(deg_e, deg_u, deg_i,
                                               base_e, base_u, base_i,
                                               gt_e, gt_u, gt_i,
                                               n_ent, n_usr, n_items, Be, Bu);

    // KG compute
    kg_edge_fused_k<<<(E_kg + 63) / 64, 256, 0, stream>>>(ent, rel, kg_src, kg_dst,
                                                          kg_typ, base_e, rank_kg,
                                                          pay_kg, E_kg);
    kg_gather_k<<<(n_ent + 3) / 4, 256, 0, stream>>>(ent, rel, deg_e, base_e, pay_kg,
                                                     out_final, out_items, normv,
                                                     n_items, n_ent);
    user_norm_k<<<(n_usr + 3) / 4, 256, 0, stream>>>(usr, normv, n_items, n_usr);

    // CF scatters (atomic-free), then gathers (iu_gather overwrites out_u AFTER
    // all rank consumers have run)
    iu_scat_k<<<(E_iu + 255) / 256, 256, 0, stream>>>(iu_src, iu_dst, base_u, rank_iu,
                                                      pay_iu, n_items, N, E_iu);
    ui_scat_k<<<(E_ui + 255) / 256, 256, 0, stream>>>(ui_src, ui_dst, normv, base_i,
                                                      rank_ui, pay_ui, n_items, E_ui);
    iu_gather_k<<<(n_usr + 3) / 4, 256, 0, stream>>>(out_items, usr, deg_u, base_u,
                                                     pay_iu, out_u, n_items, n_usr);
    ui_gather_k<<<(n_items + 3) / 4, 256, 0, stream>>>(out_items, usr, normv, deg_i,
                                                       base_i, pay_ui, icf, n_items,
                                                       n_items);
    fusion_mfma_k<<<(n_items + 63) / 64, 256, 0, stream>>>(out_items, icf, W1, W2,
                                                           out_final, n_items);
}